// Round 2
// baseline (224.622 us; speedup 1.0000x reference)
//
#include <hip/hip_runtime.h>
#include <hip/hip_bf16.h>

// NodeAggregator forward, round 2: fusion-heavy restructure.
// STE => forward output == degree-normalized pooled; top-k dead.
// Launches: T(W1) T(W2) | G1 x@W1 (f32-direct, +relu+bias, side-writes xbT)
//   -> G2 h@W2 (+bias+mask, fused softmax, writes ST only, transposed)
//   -> G3 adj@S (adj f32-direct, writes midT transposed)
//   -> G4 ST@midT (f32 out + fused rowsum->dinv) -> G5 ST@xbT -> finalize.
// All GEMMs: BM=64, BN=256, BK=32, 4 waves (2x2, wave tile 32x128),
// mfma_f32_16x16x32_bf16, C/D layout col=lane&15 row=(lane>>4)*4+reg (m89).

typedef float f32x4 __attribute__((ext_vector_type(4)));
typedef __bf16 bf16x8 __attribute__((ext_vector_type(8)));

__device__ __forceinline__ void async_load16(const void* g, void* l) {
  __builtin_amdgcn_global_load_lds((const __attribute__((address_space(1))) void*)g,
                                   (__attribute__((address_space(3))) void*)l, 16, 0, 0);
}
__device__ __forceinline__ unsigned short f2bf(float f) {
  return __builtin_bit_cast(unsigned short, (__bf16)f);
}

// out[c][r] = (bf16) in[r][c]  (weights only)
__global__ __launch_bounds__(256) void transpose_f32_bf16_k(
    const float* __restrict__ in, __bf16* __restrict__ out, int R, int C) {
  __shared__ float tile[64][65];
  const int r0 = blockIdx.y * 64, c0 = blockIdx.x * 64;
  const int tr = threadIdx.x >> 6, tc = threadIdx.x & 63;
#pragma unroll
  for (int i = 0; i < 16; ++i) {
    const int rr = tr + i * 4;
    tile[rr][tc] = in[(long long)(r0 + rr) * C + (c0 + tc)];
  }
  __syncthreads();
#pragma unroll
  for (int i = 0; i < 16; ++i) {
    const int cc = tr + i * 4;
    out[(long long)(c0 + cc) * R + (r0 + tc)] = (__bf16)tile[tc][cc];
  }
}

// EPI: 0 plain f32 out (G5) | 1 relu+bias bf16 out + xbT side-write (G1)
//      2 bias+mask fused softmax -> transposed bf16 ST (G2)
//      3 transposed bf16 out (G3 -> midT) | 4 f32 out + fused rowsum dinv (G4)
template <int EPI, bool A_F32>
__global__ __launch_bounds__(256) void gemm_bn256(
    const void* __restrict__ Ap, const __bf16* __restrict__ Bt,
    void* __restrict__ Cp, const float* __restrict__ bias,
    const float* __restrict__ mask, void* __restrict__ aux,
    int Kd, int lda, int ldb, int ldc,
    long long strideA, long long strideB, long long strideC) {
  constexpr int BM = 64, BN = 256, BK = 32;
  constexpr int FM = 2, FN = 8;
  __shared__ alignas(16) __bf16 Alds[BM * BK];
  __shared__ alignas(16) __bf16 Blds[BN * BK];
  __shared__ float red[2][4][BM];

  const int t = threadIdx.x;
  const int lane = t & 63, wave = t >> 6;
  const int l15 = lane & 15, l4 = lane >> 4;
  const int wm = (wave >> 1) * 32, wn = (wave & 1) * 128;
  const long long bm0 = (long long)blockIdx.y * BM;
  const long long bn0 = (long long)blockIdx.x * BN;
  const __bf16* Bb = Bt + (long long)blockIdx.z * strideB;

  f32x4 acc[FM][FN] = {};

  for (int kk = 0; kk < Kd; kk += BK) {
    if (A_F32) {
      const float* Af = (const float*)Ap + (long long)blockIdx.z * strideA;
#pragma unroll
      for (int c = 0; c < 2; ++c) {
        const int idx = c * 256 + t;            // 512 float4 = 64 rows x 32 k
        const int row = idx >> 3, ch = idx & 7;
        const float4 v = *(const float4*)(Af + (bm0 + row) * (long long)lda + kk + ch * 4);
        ushort4 u;
        u.x = f2bf(v.x); u.y = f2bf(v.y); u.z = f2bf(v.z); u.w = f2bf(v.w);
        *(ushort4*)&Alds[row * BK + ch * 4] = u;
        if (EPI == 1) {  // side-write x^T bf16 [512][16384]; each elem exactly once
          __bf16* xT = (__bf16*)aux;
          const long long n = bm0 + row;
          const int f = kk + ch * 4;
          xT[(long long)(f + 0) * 16384 + n] = (__bf16)v.x;
          xT[(long long)(f + 1) * 16384 + n] = (__bf16)v.y;
          xT[(long long)(f + 2) * 16384 + n] = (__bf16)v.z;
          xT[(long long)(f + 3) * 16384 + n] = (__bf16)v.w;
        }
      }
    } else {
      const __bf16* Ab = (const __bf16*)Ap + (long long)blockIdx.z * strideA;
      const int row = t >> 2, ch = t & 3;       // 256 chunks of 16B
      async_load16(Ab + (bm0 + row) * (long long)lda + kk + ch * 8, &Alds[t * 8]);
    }
#pragma unroll
    for (int c = 0; c < 4; ++c) {               // B: 256 rows x 32 k bf16 = 1024x16B
      const int idx = c * 256 + t;
      const int row = idx >> 2, ch = idx & 3;
      async_load16(Bb + (bn0 + row) * (long long)ldb + kk + ch * 8, &Blds[idx * 8]);
    }
    __syncthreads();
    bf16x8 af[FM], bfr[FN];
#pragma unroll
    for (int i = 0; i < FM; ++i)
      af[i] = *(const bf16x8*)&Alds[(wm + i * 16 + l15) * BK + l4 * 8];
#pragma unroll
    for (int j = 0; j < FN; ++j)
      bfr[j] = *(const bf16x8*)&Blds[(wn + j * 16 + l15) * BK + l4 * 8];
#pragma unroll
    for (int i = 0; i < FM; ++i)
#pragma unroll
      for (int j = 0; j < FN; ++j)
        acc[i][j] = __builtin_amdgcn_mfma_f32_16x16x32_bf16(af[i], bfr[j], acc[i][j], 0, 0, 0);
    __syncthreads();
  }

  // ---------------- epilogues ----------------
  if (EPI == 0 || EPI == 4) {
    float* C = (float*)Cp + (long long)blockIdx.z * strideC;
#pragma unroll
    for (int i = 0; i < FM; ++i)
#pragma unroll
      for (int j = 0; j < FN; ++j)
#pragma unroll
        for (int r = 0; r < 4; ++r)
          C[(bm0 + wm + i * 16 + l4 * 4 + r) * (long long)ldc + bn0 + wn + j * 16 + l15] =
              acc[i][j][r];
    if (EPI == 4) {  // fused row-sum -> dinv (full row: BN=256==K)
      float s[FM][4];
#pragma unroll
      for (int i = 0; i < FM; ++i)
#pragma unroll
        for (int r = 0; r < 4; ++r) {
          float v = 0.f;
#pragma unroll
          for (int j = 0; j < FN; ++j) v += acc[i][j][r];
#pragma unroll
          for (int o = 8; o > 0; o >>= 1) v += __shfl_xor(v, o, 64);
          s[i][r] = v;
        }
      if (l15 == 0)
#pragma unroll
        for (int i = 0; i < FM; ++i)
#pragma unroll
          for (int r = 0; r < 4; ++r) red[0][wave][wm + i * 16 + l4 * 4 + r] = s[i][r];
      __syncthreads();
      if ((wave & 1) == 0 && l15 == 0) {
        float* dinv = (float*)aux;
#pragma unroll
        for (int i = 0; i < FM; ++i)
#pragma unroll
          for (int r = 0; r < 4; ++r) {
            const int rl = wm + i * 16 + l4 * 4 + r;
            dinv[blockIdx.z * 256 + blockIdx.y * 64 + rl] =
                rsqrtf(s[i][r] + red[0][wave ^ 1][rl] + 1e-9f);
          }
      }
    }
  }

  if (EPI == 1) {  // h = relu(acc + bias), bf16 row-major
    __bf16* C = (__bf16*)Cp;
#pragma unroll
    for (int j = 0; j < FN; ++j) {
      const int col = wn + j * 16 + l15;
      const float bv = bias[col];
#pragma unroll
      for (int i = 0; i < FM; ++i)
#pragma unroll
        for (int r = 0; r < 4; ++r) {
          const long long row = bm0 + wm + i * 16 + l4 * 4 + r;
          C[row * 256 + col] = (__bf16)fmaxf(acc[i][j][r] + bv, 0.f);
        }
    }
  }

  if (EPI == 2) {  // masked softmax over the full 256-col row, write S^T
    float mb[FM][4], mx[FM][4], sm[FM][4];
#pragma unroll
    for (int i = 0; i < FM; ++i)
#pragma unroll
      for (int r = 0; r < 4; ++r) {
        mb[i][r] = -1e9f * (1.0f - mask[bm0 + wm + i * 16 + l4 * 4 + r]);
        mx[i][r] = -3.4e38f;
        sm[i][r] = 0.f;
      }
#pragma unroll
    for (int j = 0; j < FN; ++j) {
      const float bv = bias[wn + j * 16 + l15];
#pragma unroll
      for (int i = 0; i < FM; ++i)
#pragma unroll
        for (int r = 0; r < 4; ++r) {
          const float v = acc[i][j][r] + bv + mb[i][r];
          acc[i][j][r] = v;
          mx[i][r] = fmaxf(mx[i][r], v);
        }
    }
#pragma unroll
    for (int i = 0; i < FM; ++i)
#pragma unroll
      for (int r = 0; r < 4; ++r) {
#pragma unroll
        for (int o = 8; o > 0; o >>= 1) mx[i][r] = fmaxf(mx[i][r], __shfl_xor(mx[i][r], o, 64));
      }
    if (l15 == 0)
#pragma unroll
      for (int i = 0; i < FM; ++i)
#pragma unroll
        for (int r = 0; r < 4; ++r) red[0][wave][wm + i * 16 + l4 * 4 + r] = mx[i][r];
    __syncthreads();
#pragma unroll
    for (int i = 0; i < FM; ++i)
#pragma unroll
      for (int r = 0; r < 4; ++r)
        mx[i][r] = fmaxf(mx[i][r], red[0][wave ^ 1][wm + i * 16 + l4 * 4 + r]);
#pragma unroll
    for (int j = 0; j < FN; ++j)
#pragma unroll
      for (int i = 0; i < FM; ++i)
#pragma unroll
        for (int r = 0; r < 4; ++r) {
          const float e = __expf(acc[i][j][r] - mx[i][r]);
          acc[i][j][r] = e;
          sm[i][r] += e;
        }
#pragma unroll
    for (int i = 0; i < FM; ++i)
#pragma unroll
      for (int r = 0; r < 4; ++r) {
#pragma unroll
        for (int o = 8; o > 0; o >>= 1) sm[i][r] += __shfl_xor(sm[i][r], o, 64);
      }
    if (l15 == 0)
#pragma unroll
      for (int i = 0; i < FM; ++i)
#pragma unroll
        for (int r = 0; r < 4; ++r) red[1][wave][wm + i * 16 + l4 * 4 + r] = sm[i][r];
    __syncthreads();
    float inv[FM][4];
#pragma unroll
    for (int i = 0; i < FM; ++i)
#pragma unroll
      for (int r = 0; r < 4; ++r)
        inv[i][r] = 1.0f / (sm[i][r] + red[1][wave ^ 1][wm + i * 16 + l4 * 4 + r]);
    // transposed store: lane holds 4 consecutive rows (n) per reg quad -> ushort4
    __bf16* ST = (__bf16*)Cp;
    const long long b = bm0 >> 11;
    const long long nin = (bm0 & 2047) + wm + l4 * 4;
#pragma unroll
    for (int j = 0; j < FN; ++j) {
      const int col = wn + j * 16 + l15;
#pragma unroll
      for (int i = 0; i < FM; ++i) {
        ushort4 u;
        u.x = f2bf(acc[i][j][0] * inv[i][0]);
        u.y = f2bf(acc[i][j][1] * inv[i][1]);
        u.z = f2bf(acc[i][j][2] * inv[i][2]);
        u.w = f2bf(acc[i][j][3] * inv[i][3]);
        *(ushort4*)(ST + b * strideC + (long long)col * ldc + nin + i * 16) = u;
      }
    }
  }

  if (EPI == 3) {  // transposed bf16 out (midT[l][n])
    __bf16* C = (__bf16*)Cp + (long long)blockIdx.z * strideC;
    const long long nin = bm0 + wm + l4 * 4;
#pragma unroll
    for (int j = 0; j < FN; ++j) {
      const int col = wn + j * 16 + l15;
#pragma unroll
      for (int i = 0; i < FM; ++i) {
        ushort4 u;
        u.x = f2bf(acc[i][j][0]);
        u.y = f2bf(acc[i][j][1]);
        u.z = f2bf(acc[i][j][2]);
        u.w = f2bf(acc[i][j][3]);
        *(ushort4*)(C + (long long)col * ldc + nin + i * 16) = u;
      }
    }
  }
}

__global__ __launch_bounds__(256) void finalize_k(const float* __restrict__ pooled,
                                                  const float* __restrict__ dinv,
                                                  float* __restrict__ outAdj,
                                                  float* __restrict__ pmask) {
  const long long i = blockIdx.x * 256LL + threadIdx.x;  // 524288 = 8*256*256
  const int c = (int)(i & 255);
  const int r = (int)((i >> 8) & 255);
  const int b = (int)(i >> 16);
  outAdj[i] = pooled[i] * dinv[b * 256 + r] * dinv[b * 256 + c];
  if (i < 2048) pmask[i] = 1.0f;
}

extern "C" void kernel_launch(void* const* d_in, const int* in_sizes, int n_in,
                              void* d_out, int out_size, void* d_ws, size_t ws_size,
                              hipStream_t stream) {
  (void)in_sizes; (void)n_in; (void)out_size; (void)ws_size;
  const float* x    = (const float*)d_in[0];  // [8,2048,512]
  const float* adj  = (const float*)d_in[1];  // [8,2048,2048]
  const float* mask = (const float*)d_in[2];  // [8,2048]
  const float* W1   = (const float*)d_in[3];  // [512,256]
  const float* b1   = (const float*)d_in[4];  // [256]
  const float* W2   = (const float*)d_in[5];  // [256,256]
  const float* b2   = (const float*)d_in[6];  // [256]

  char* ws = (char*)d_ws;  // total 44,441,600 B (~42.4 MiB)
  __bf16* ST     = (__bf16*)(ws + 0);           //  8,388,608  [8][256][2048]
  __bf16* midT   = (__bf16*)(ws + 8388608);     //  8,388,608  [8][256][2048]
  __bf16* h      = (__bf16*)(ws + 16777216);    //  8,388,608  [16384][256]
  __bf16* xbT    = (__bf16*)(ws + 25165824);    // 16,777,216  [512][16384]
  float*  pooled = (float*)(ws + 41943040);     //  2,097,152  [8][256][256]
  float*  dinv   = (float*)(ws + 44040192);     //      8,192  [8][256]
  __bf16* W1T    = (__bf16*)(ws + 44048384);    //    262,144  [256][512]
  __bf16* W2T    = (__bf16*)(ws + 44310528);    //    131,072  [256][256]

  float* pfeat  = (float*)d_out;                // [8,256,512]
  float* outAdj = (float*)d_out + 1048576;      // [8,256,256]
  float* pmask  = (float*)d_out + 1572864;      // [8,256]

  transpose_f32_bf16_k<<<dim3(4, 8, 1), 256, 0, stream>>>(W1, W1T, 512, 256);
  transpose_f32_bf16_k<<<dim3(4, 4, 1), 256, 0, stream>>>(W2, W2T, 256, 256);

  // G1: h = relu(x @ W1 + b1), x read as f32 once; side-writes xbT
  gemm_bn256<1, true><<<dim3(1, 256, 1), 256, 0, stream>>>(
      x, W1T, h, b1, nullptr, xbT, 512, 512, 512, 256, 0, 0, 0);
  // G2: logits = h @ W2 + b2, fused masked softmax, writes ST (transposed) only
  gemm_bn256<2, false><<<dim3(1, 256, 1), 256, 0, stream>>>(
      h, W2T, ST, b2, mask, nullptr, 256, 256, 256, 2048, 0, 0, 524288);
  // G3: midT = (adj @ S)^T, adj read as f32 exactly once
  gemm_bn256<3, true><<<dim3(1, 32, 8), 256, 0, stream>>>(
      adj, ST, midT, nullptr, nullptr, nullptr, 2048, 2048, 2048, 2048,
      4194304, 524288, 524288);
  // G4: pooled = S^T @ mid (f32) + fused rowsum -> dinv
  gemm_bn256<4, false><<<dim3(1, 4, 8), 256, 0, stream>>>(
      ST, midT, pooled, nullptr, nullptr, dinv, 2048, 2048, 2048, 256,
      524288, 524288, 65536);
  // G5: pfeat = S^T @ x -> d_out
  gemm_bn256<0, false><<<dim3(2, 4, 8), 256, 0, stream>>>(
      ST, xbT, pfeat, nullptr, nullptr, nullptr, 2048, 2048, 16384, 512,
      524288, 2048, 131072);
  // degree renorm + pmask
  finalize_k<<<2048, 256, 0, stream>>>(pooled, dinv, outAdj, pmask);
}

// Round 3
// 133.524 us; speedup vs baseline: 1.6823x; 1.6823x over previous
//
#include <hip/hip_runtime.h>
#include <hip/hip_bf16.h>

// NodeAggregator forward, round 3: parallelism + pipelining restructure.
// STE => forward output == degree-normalized pooled; top-k dead.
// Launches: prep(W1T,W2T) -> assign_fused (x@W1 relu -> @W2 +b -> masked softmax -> ST)
//   -> gemm_feat (pfeat partials, split-K8) -> reduce_feat
//   -> gemm_adj (midT = (adj@S)^T, adj f32 once) -> gemm_pool (split-K4) -> reduce_pool -> finalize.
// All GEMMs: mfma 16x16x32 bf16, LDS double-buffer, T14 issue-early/write-late,
// T2 swizzle (pre-swizzled gloadlds source + XOR'd frag reads).

typedef float f32x4 __attribute__((ext_vector_type(4)));
typedef __bf16 bf16x8 __attribute__((ext_vector_type(8)));

__device__ __forceinline__ void async_load16(const void* g, void* l) {
  __builtin_amdgcn_global_load_lds((const __attribute__((address_space(1))) void*)g,
                                   (__attribute__((address_space(3))) void*)l, 16, 0, 0);
}
__device__ __forceinline__ unsigned short f2bf(float f) {
  return __builtin_bit_cast(unsigned short, (__bf16)f);
}
__device__ __forceinline__ ushort4 f4_to_bf4(float4 v) {
  ushort4 u; u.x = f2bf(v.x); u.y = f2bf(v.y); u.z = f2bf(v.z); u.w = f2bf(v.w); return u;
}

// Stage a [ROWS][BK] bf16 tile (row-major src, leading dim ld) into linear LDS via
// global_load_lds, with T2 XOR swizzle applied on the SOURCE granule (rule #21).
template <int ROWS, int BK, int NT>
__device__ __forceinline__ void stage_bf16(const __bf16* __restrict__ src, long long ld,
                                           __bf16* lds, int t) {
  constexpr int GR = BK / 8;  // 16B granules per row
  constexpr int N = ROWS * GR / NT;
#pragma unroll
  for (int c = 0; c < N; ++c) {
    const int idx = c * NT + t;
    const int row = idx / GR;
    const int g = idx % GR;
    const int gs = g ^ (row & (GR - 1) & 7);
    async_load16(src + (long long)row * ld + gs * 8, lds + idx * 8);
  }
}
// Matching swizzled fragment read. kq = k-granule index = ksub*4 + (lane>>4).
template <int BK>
__device__ __forceinline__ bf16x8 frag(const __bf16* lds, int row, int kq) {
  constexpr int GR = BK / 8;
  const int g = kq ^ (row & (GR - 1) & 7);
  return *(const bf16x8*)(lds + row * BK + g * 8);
}

// ---------------- weight transposes (tiny) ----------------
__global__ __launch_bounds__(256) void prep_weights_k(const float* __restrict__ W1,
                                                      const float* __restrict__ W2,
                                                      __bf16* __restrict__ W1T,
                                                      __bf16* __restrict__ W2T) {
  __shared__ float tile[64][65];
  int bid = blockIdx.x;
  const float* in; __bf16* out; int R, C;
  if (bid < 32) { in = W1; out = W1T; R = 512; C = 256; }
  else { bid -= 32; in = W2; out = W2T; R = 256; C = 256; }
  const int r0 = (bid >> 2) * 64, c0 = (bid & 3) * 64;
  const int tr = threadIdx.x >> 6, tc = threadIdx.x & 63;
#pragma unroll
  for (int i = 0; i < 16; ++i)
    tile[tr + i * 4][tc] = in[(long long)(r0 + tr + i * 4) * C + c0 + tc];
  __syncthreads();
#pragma unroll
  for (int i = 0; i < 16; ++i)
    out[(long long)(c0 + tr + i * 4) * R + r0 + tc] = (__bf16)tile[tc][tr + i * 4];
}

// ---------------- fused assign: x -> relu(xW1+b1) -> W2+b2 -> masked softmax -> ST ----
// BM=32 rows/block, 512 blocks, 4 waves each owning a 64-col strip of the 256 clusters.
__global__ __launch_bounds__(256) void assign_fused_k(
    const float* __restrict__ x, const __bf16* __restrict__ W1T,
    const __bf16* __restrict__ W2T, const float* __restrict__ b1,
    const float* __restrict__ b2, const float* __restrict__ mask,
    __bf16* __restrict__ ST) {
  __shared__ alignas(16) __bf16 Ax[2][32 * 32];
  __shared__ alignas(16) __bf16 Bw[2][256 * 32];
  __shared__ alignas(16) __bf16 hl[32 * 264];  // pad 8 to break b128 stride conflicts
  __shared__ float red[2][4][32];

  const int t = threadIdx.x;
  const int lane = t & 63, wave = t >> 6;
  const int l15 = lane & 15, l4 = lane >> 4;
  const int wn = wave * 64;
  const long long row0 = (long long)blockIdx.y * 32;
  const float* Xb = x + row0 * 512;

  const int arow = t >> 3, afq = t & 7;  // 1 float4/thread: 32 rows x 8 f4-chunks
  const int aoff = arow * 32 + (((afq >> 1) ^ (arow & 3)) * 8) + (afq & 1) * 4;

  f32x4 acc[2][4] = {};

  float4 va = *(const float4*)(Xb + (long long)arow * 512 + afq * 4);
  stage_bf16<256, 32, 256>(W1T, 512, Bw[0], t);
  *(ushort4*)&Ax[0][aoff] = f4_to_bf4(va);
  __syncthreads();

  for (int tt = 0; tt < 16; ++tt) {  // K=512, BK=32
    const int cur = tt & 1, nxt = cur ^ 1;
    float4 na;
    if (tt < 15) {
      const int kk = (tt + 1) * 32;
      na = *(const float4*)(Xb + (long long)arow * 512 + kk + afq * 4);
      stage_bf16<256, 32, 256>(W1T + kk, 512, Bw[nxt], t);
    }
    bf16x8 af[2], bfr[4];
#pragma unroll
    for (int i = 0; i < 2; ++i) af[i] = frag<32>(Ax[cur], i * 16 + l15, l4);
#pragma unroll
    for (int j = 0; j < 4; ++j) bfr[j] = frag<32>(Bw[cur], wn + j * 16 + l15, l4);
#pragma unroll
    for (int i = 0; i < 2; ++i)
#pragma unroll
      for (int j = 0; j < 4; ++j)
        acc[i][j] = __builtin_amdgcn_mfma_f32_16x16x32_bf16(af[i], bfr[j], acc[i][j], 0, 0, 0);
    if (tt < 15) *(ushort4*)&Ax[nxt][aoff] = f4_to_bf4(na);
    __syncthreads();
  }

  // h (relu + b1) -> LDS; prefetch phase-B k0 (Bw[0] free after last barrier)
  stage_bf16<256, 32, 256>(W2T, 256, Bw[0], t);
#pragma unroll
  for (int j = 0; j < 4; ++j) {
    const int col = wn + j * 16 + l15;
    const float bv = b1[col];
#pragma unroll
    for (int i = 0; i < 2; ++i)
#pragma unroll
      for (int r = 0; r < 4; ++r)
        hl[(i * 16 + l4 * 4 + r) * 264 + col] = (__bf16)fmaxf(acc[i][j][r] + bv, 0.f);
  }
  __syncthreads();

  f32x4 acc2[2][4] = {};
  for (int tt = 0; tt < 8; ++tt) {  // K=256, BK=32
    const int cur = tt & 1, nxt = cur ^ 1;
    if (tt < 7) stage_bf16<256, 32, 256>(W2T + (tt + 1) * 32, 256, Bw[nxt], t);
    bf16x8 af[2], bfr[4];
#pragma unroll
    for (int i = 0; i < 2; ++i)
      af[i] = *(const bf16x8*)(&hl[(i * 16 + l15) * 264 + tt * 32 + l4 * 8]);
#pragma unroll
    for (int j = 0; j < 4; ++j) bfr[j] = frag<32>(Bw[cur], wn + j * 16 + l15, l4);
#pragma unroll
    for (int i = 0; i < 2; ++i)
#pragma unroll
      for (int j = 0; j < 4; ++j)
        acc2[i][j] = __builtin_amdgcn_mfma_f32_16x16x32_bf16(af[i], bfr[j], acc2[i][j], 0, 0, 0);
    __syncthreads();
  }

  // masked softmax across the full 256 cols (4 waves), then transposed ST store
  float mb[2][4], mx[2][4], sm[2][4];
#pragma unroll
  for (int i = 0; i < 2; ++i)
#pragma unroll
    for (int r = 0; r < 4; ++r) {
      mb[i][r] = -1e9f * (1.0f - mask[row0 + i * 16 + l4 * 4 + r]);
      mx[i][r] = -3.4e38f;
      sm[i][r] = 0.f;
    }
#pragma unroll
  for (int j = 0; j < 4; ++j) {
    const float bv = b2[wn + j * 16 + l15];
#pragma unroll
    for (int i = 0; i < 2; ++i)
#pragma unroll
      for (int r = 0; r < 4; ++r) {
        const float v = acc2[i][j][r] + bv + mb[i][r];
        acc2[i][j][r] = v;
        mx[i][r] = fmaxf(mx[i][r], v);
      }
  }
#pragma unroll
  for (int i = 0; i < 2; ++i)
#pragma unroll
    for (int r = 0; r < 4; ++r) {
      float m = mx[i][r];
      m = fmaxf(m, __shfl_xor(m, 1, 64)); m = fmaxf(m, __shfl_xor(m, 2, 64));
      m = fmaxf(m, __shfl_xor(m, 4, 64)); m = fmaxf(m, __shfl_xor(m, 8, 64));
      mx[i][r] = m;
    }
  if (l15 == 0)
#pragma unroll
    for (int i = 0; i < 2; ++i)
#pragma unroll
      for (int r = 0; r < 4; ++r) red[0][wave][i * 16 + l4 * 4 + r] = mx[i][r];
  __syncthreads();
#pragma unroll
  for (int i = 0; i < 2; ++i)
#pragma unroll
    for (int r = 0; r < 4; ++r) {
      const int rl = i * 16 + l4 * 4 + r;
      mx[i][r] = fmaxf(fmaxf(red[0][0][rl], red[0][1][rl]),
                       fmaxf(red[0][2][rl], red[0][3][rl]));
    }
#pragma unroll
  for (int j = 0; j < 4; ++j)
#pragma unroll
    for (int i = 0; i < 2; ++i)
#pragma unroll
      for (int r = 0; r < 4; ++r) {
        const float e = __expf(acc2[i][j][r] - mx[i][r]);
        acc2[i][j][r] = e;
        sm[i][r] += e;
      }
#pragma unroll
  for (int i = 0; i < 2; ++i)
#pragma unroll
    for (int r = 0; r < 4; ++r) {
      float s = sm[i][r];
      s += __shfl_xor(s, 1, 64); s += __shfl_xor(s, 2, 64);
      s += __shfl_xor(s, 4, 64); s += __shfl_xor(s, 8, 64);
      sm[i][r] = s;
    }
  if (l15 == 0)
#pragma unroll
    for (int i = 0; i < 2; ++i)
#pragma unroll
      for (int r = 0; r < 4; ++r) red[1][wave][i * 16 + l4 * 4 + r] = sm[i][r];
  __syncthreads();
  float inv[2][4];
#pragma unroll
  for (int i = 0; i < 2; ++i)
#pragma unroll
    for (int r = 0; r < 4; ++r) {
      const int rl = i * 16 + l4 * 4 + r;
      inv[i][r] = 1.0f / (red[1][0][rl] + red[1][1][rl] + red[1][2][rl] + red[1][3][rl]);
    }
  const long long bb = row0 >> 11;
  const long long n0 = row0 & 2047;
  __bf16* Sb = ST + bb * 524288;
#pragma unroll
  for (int j = 0; j < 4; ++j) {
    const int col = wn + j * 16 + l15;
#pragma unroll
    for (int i = 0; i < 2; ++i) {
      ushort4 u;
      u.x = f2bf(acc2[i][j][0] * inv[i][0]);
      u.y = f2bf(acc2[i][j][1] * inv[i][1]);
      u.z = f2bf(acc2[i][j][2] * inv[i][2]);
      u.w = f2bf(acc2[i][j][3] * inv[i][3]);
      *(ushort4*)(Sb + (long long)col * 2048 + n0 + i * 16 + l4 * 4) = u;
    }
  }
}

// ---------------- G3: midT = (adj @ S)^T, adj read f32 exactly once ----------------
// BM=32 adj rows, BN=256 (all clusters), BK=64; 512 blocks, 2/CU.
__global__ __launch_bounds__(256) void gemm_adj_k(const float* __restrict__ adj,
                                                  const __bf16* __restrict__ ST,
                                                  __bf16* __restrict__ midT) {
  __shared__ alignas(16) __bf16 Aa[2][32 * 64];
  __shared__ alignas(16) __bf16 Bs[2][256 * 64];
  const int t = threadIdx.x;
  const int lane = t & 63, wave = t >> 6;
  const int l15 = lane & 15, l4 = lane >> 4;
  const int wn = wave * 64;
  const int bz = blockIdx.z;
  const long long r0 = (long long)blockIdx.y * 32;
  const float* Ab = adj + (long long)bz * 4194304 + r0 * 2048;
  const __bf16* Bb = ST + (long long)bz * 524288;

  const int arow = t >> 4, afq = t & 15;  // 2 float4/thread: rows arow, arow+16
  const int arow1 = arow + 16;
  const int aoff0 = arow * 64 + (((afq >> 1) ^ (arow & 7)) * 8) + (afq & 1) * 4;
  const int aoff1 = arow1 * 64 + (((afq >> 1) ^ (arow1 & 7)) * 8) + (afq & 1) * 4;

  f32x4 acc[2][4] = {};

  float4 va0 = *(const float4*)(Ab + (long long)arow * 2048 + afq * 4);
  float4 va1 = *(const float4*)(Ab + (long long)arow1 * 2048 + afq * 4);
  stage_bf16<256, 64, 256>(Bb, 2048, Bs[0], t);
  *(ushort4*)&Aa[0][aoff0] = f4_to_bf4(va0);
  *(ushort4*)&Aa[0][aoff1] = f4_to_bf4(va1);
  __syncthreads();

  for (int tt = 0; tt < 32; ++tt) {  // K=2048, BK=64
    const int cur = tt & 1, nxt = cur ^ 1;
    float4 na0, na1;
    if (tt < 31) {
      const int kk = (tt + 1) * 64;
      na0 = *(const float4*)(Ab + (long long)arow * 2048 + kk + afq * 4);
      na1 = *(const float4*)(Ab + (long long)arow1 * 2048 + kk + afq * 4);
      stage_bf16<256, 64, 256>(Bb + kk, 2048, Bs[nxt], t);
    }
#pragma unroll
    for (int ks = 0; ks < 2; ++ks) {
      bf16x8 af[2], bfr[4];
#pragma unroll
      for (int i = 0; i < 2; ++i) af[i] = frag<64>(Aa[cur], i * 16 + l15, ks * 4 + l4);
#pragma unroll
      for (int j = 0; j < 4; ++j) bfr[j] = frag<64>(Bs[cur], wn + j * 16 + l15, ks * 4 + l4);
#pragma unroll
      for (int i = 0; i < 2; ++i)
#pragma unroll
        for (int j = 0; j < 4; ++j)
          acc[i][j] = __builtin_amdgcn_mfma_f32_16x16x32_bf16(af[i], bfr[j], acc[i][j], 0, 0, 0);
    }
    if (tt < 31) {
      *(ushort4*)&Aa[nxt][aoff0] = f4_to_bf4(na0);
      *(ushort4*)&Aa[nxt][aoff1] = f4_to_bf4(na1);
    }
    __syncthreads();
  }

  __bf16* Cb = midT + (long long)bz * 524288;
#pragma unroll
  for (int j = 0; j < 4; ++j) {
    const int l = wn + j * 16 + l15;
#pragma unroll
    for (int i = 0; i < 2; ++i) {
      ushort4 u;
      u.x = f2bf(acc[i][j][0]); u.y = f2bf(acc[i][j][1]);
      u.z = f2bf(acc[i][j][2]); u.w = f2bf(acc[i][j][3]);
      *(ushort4*)(Cb + (long long)l * 2048 + r0 + i * 16 + l4 * 4) = u;
    }
  }
}

// ---------------- G4: pooled partials = ST @ midT^T, split-K x4 ----------------
__global__ __launch_bounds__(256) void gemm_pool_k(const __bf16* __restrict__ ST,
                                                   const __bf16* __restrict__ midT,
                                                   float* __restrict__ partP) {
  __shared__ alignas(16) __bf16 As[2][64 * 64];
  __shared__ alignas(16) __bf16 Bs[2][64 * 64];
  const int t = threadIdx.x;
  const int lane = t & 63, wave = t >> 6;
  const int l15 = lane & 15, l4 = lane >> 4;
  const int wm = (wave >> 1) * 32, wn = (wave & 1) * 32;
  const int b = blockIdx.z >> 2, ks = blockIdx.z & 3;
  const long long row0 = (long long)blockIdx.y * 64, col0 = (long long)blockIdx.x * 64;
  const __bf16* Ab = ST + (long long)b * 524288 + row0 * 2048 + ks * 512;
  const __bf16* Bb = midT + (long long)b * 524288 + col0 * 2048 + ks * 512;

  f32x4 acc[2][2] = {};
  stage_bf16<64, 64, 256>(Ab, 2048, As[0], t);
  stage_bf16<64, 64, 256>(Bb, 2048, Bs[0], t);
  __syncthreads();
  for (int tt = 0; tt < 8; ++tt) {  // K=512, BK=64
    const int cur = tt & 1, nxt = cur ^ 1;
    if (tt < 7) {
      stage_bf16<64, 64, 256>(Ab + (tt + 1) * 64, 2048, As[nxt], t);
      stage_bf16<64, 64, 256>(Bb + (tt + 1) * 64, 2048, Bs[nxt], t);
    }
#pragma unroll
    for (int ksb = 0; ksb < 2; ++ksb) {
      bf16x8 af[2], bfr[2];
#pragma unroll
      for (int i = 0; i < 2; ++i) af[i] = frag<64>(As[cur], wm + i * 16 + l15, ksb * 4 + l4);
#pragma unroll
      for (int j = 0; j < 2; ++j) bfr[j] = frag<64>(Bs[cur], wn + j * 16 + l15, ksb * 4 + l4);
#pragma unroll
      for (int i = 0; i < 2; ++i)
#pragma unroll
        for (int j = 0; j < 2; ++j)
          acc[i][j] = __builtin_amdgcn_mfma_f32_16x16x32_bf16(af[i], bfr[j], acc[i][j], 0, 0, 0);
    }
    __syncthreads();
  }
  float* out = partP + (long long)blockIdx.z * 65536;
#pragma unroll
  for (int i = 0; i < 2; ++i)
#pragma unroll
    for (int j = 0; j < 2; ++j)
#pragma unroll
      for (int r = 0; r < 4; ++r)
        out[(row0 + wm + i * 16 + l4 * 4 + r) * 256 + col0 + wn + j * 16 + l15] = acc[i][j][r];
}

// ---------------- G5: pfeat partials = ST @ x, split-K x8, x f32 transpose-staged ----
__global__ __launch_bounds__(512) void gemm_feat_k(const __bf16* __restrict__ ST,
                                                   const float* __restrict__ x,
                                                   float* __restrict__ partF) {
  __shared__ alignas(16) __bf16 As[2][256 * 32];
  __shared__ alignas(16) __bf16 Bx[2][128 * 40];  // [f][n] pad->40 (80B, 16B-aligned rows)
  const int t = threadIdx.x;
  const int lane = t & 63, wave = t >> 6;
  const int l15 = lane & 15, l4 = lane >> 4;
  const int wm = (wave >> 2) * 128, wn = (wave & 3) * 32;
  const int b = blockIdx.z >> 3, ks = blockIdx.z & 7;
  const int f0 = blockIdx.x * 128;
  const __bf16* Ab = ST + (long long)b * 524288 + ks * 256;
  const float* Xb = x + (long long)b * 1048576 + (long long)ks * 256 * 512 + f0;

  const int xn0 = t >> 5, xfq = t & 31;  // 2 float4/thread: n-halves 0..15, 16..31
  f32x4 acc[8][2] = {};

  auto ldx = [&](int kk, int c) -> float4 {
    return *(const float4*)(Xb + (long long)(kk + c * 16 + xn0) * 512 + xfq * 4);
  };
  auto stx = [&](int buf, float4 v, int c) {
    const int n = c * 16 + xn0;
    Bx[buf][(xfq * 4 + 0) * 40 + n] = (__bf16)v.x;
    Bx[buf][(xfq * 4 + 1) * 40 + n] = (__bf16)v.y;
    Bx[buf][(xfq * 4 + 2) * 40 + n] = (__bf16)v.z;
    Bx[buf][(xfq * 4 + 3) * 40 + n] = (__bf16)v.w;
  };

  float4 vb0 = ldx(0, 0), vb1 = ldx(0, 1);
  stage_bf16<256, 32, 512>(Ab, 2048, As[0], t);
  stx(0, vb0, 0); stx(0, vb1, 1);
  __syncthreads();
  for (int tt = 0; tt < 8; ++tt) {  // K=256, BK=32
    const int cur = tt & 1, nxt = cur ^ 1;
    float4 n0, n1;
    if (tt < 7) {
      n0 = ldx((tt + 1) * 32, 0); n1 = ldx((tt + 1) * 32, 1);
      stage_bf16<256, 32, 512>(Ab + (tt + 1) * 32, 2048, As[nxt], t);
    }
    bf16x8 af[8], bfr[2];
#pragma unroll
    for (int i = 0; i < 8; ++i) af[i] = frag<32>(As[cur], wm + i * 16 + l15, l4);
#pragma unroll
    for (int j = 0; j < 2; ++j)
      bfr[j] = *(const bf16x8*)(&Bx[cur][(wn + j * 16 + l15) * 40 + l4 * 8]);
#pragma unroll
    for (int i = 0; i < 8; ++i)
#pragma unroll
      for (int j = 0; j < 2; ++j)
        acc[i][j] = __builtin_amdgcn_mfma_f32_16x16x32_bf16(af[i], bfr[j], acc[i][j], 0, 0, 0);
    if (tt < 7) { stx(nxt, n0, 0); stx(nxt, n1, 1); }
    __syncthreads();
  }
  float* out = partF + (long long)blockIdx.z * 131072;
#pragma unroll
  for (int i = 0; i < 8; ++i)
#pragma unroll
    for (int j = 0; j < 2; ++j)
#pragma unroll
      for (int r = 0; r < 4; ++r)
        out[(wm + i * 16 + l4 * 4 + r) * 512 + f0 + wn + j * 16 + l15] = acc[i][j][r];
}

// ---------------- reducers / finalize ----------------
__global__ __launch_bounds__(256) void reduce_pool_k(const float* __restrict__ partP,
                                                     float* __restrict__ pooled,
                                                     float* __restrict__ dinv) {
  const int gr = blockIdx.x * 4 + (threadIdx.x >> 6);  // 0..2047 = b*256+row
  const int lane = threadIdx.x & 63;
  const int b = gr >> 8, row = gr & 255;
  const long long base = (long long)b * 4 * 65536 + (long long)row * 256;
  float s = 0.f;
#pragma unroll
  for (int q = 0; q < 4; ++q) {
    const int c = lane + q * 64;
    float v = partP[base + c] + partP[base + 65536 + c] +
              partP[base + 131072 + c] + partP[base + 196608 + c];
    pooled[(long long)gr * 256 + c] = v;
    s += v;
  }
#pragma unroll
  for (int o = 32; o > 0; o >>= 1) s += __shfl_xor(s, o, 64);
  if (lane == 0) dinv[gr] = rsqrtf(s + 1e-9f);
}

__global__ __launch_bounds__(256) void reduce_feat_k(const float* __restrict__ partF,
                                                     float* __restrict__ pfeat) {
  const long long p = blockIdx.x * 256LL + threadIdx.x;  // f4 id, total 262144
  const int b = (int)(p >> 15), rc = (int)(p & 32767);
  const float4* src = (const float4*)partF;
  float4 a = {0.f, 0.f, 0.f, 0.f};
#pragma unroll
  for (int ks = 0; ks < 8; ++ks) {
    const float4 v = src[(long long)(b * 8 + ks) * 32768 + rc];
    a.x += v.x; a.y += v.y; a.z += v.z; a.w += v.w;
  }
  ((float4*)pfeat)[p] = a;
}

__global__ __launch_bounds__(256) void finalize_k(const float* __restrict__ pooled,
                                                  const float* __restrict__ dinv,
                                                  float* __restrict__ outAdj,
                                                  float* __restrict__ pmask) {
  const long long i = blockIdx.x * 256LL + threadIdx.x;  // 524288
  const int c = (int)(i & 255);
  const int r = (int)((i >> 8) & 255);
  const int b = (int)(i >> 16);
  outAdj[i] = pooled[i] * dinv[b * 256 + r] * dinv[b * 256 + c];
  if (i < 2048) pmask[i] = 1.0f;
}

extern "C" void kernel_launch(void* const* d_in, const int* in_sizes, int n_in,
                              void* d_out, int out_size, void* d_ws, size_t ws_size,
                              hipStream_t stream) {
  (void)in_sizes; (void)n_in; (void)out_size; (void)ws_size;
  const float* x    = (const float*)d_in[0];  // [8,2048,512]
  const float* adj  = (const float*)d_in[1];  // [8,2048,2048]
  const float* mask = (const float*)d_in[2];  // [8,2048]
  const float* W1   = (const float*)d_in[3];  // [512,256]
  const float* b1   = (const float*)d_in[4];  // [256]
  const float* W2   = (const float*)d_in[5];  // [256,256]
  const float* b2   = (const float*)d_in[6];  // [256]

  char* ws = (char*)d_ws;  // total 61,218,816 B
  __bf16* ST     = (__bf16*)(ws + 0);          //  8,388,608  [8][256][2048]
  __bf16* midT   = (__bf16*)(ws + 8388608);    //  8,388,608  [8][256][2048]
  float*  partP  = (float*)(ws + 16777216);    //  8,388,608  [32][256][256]
  float*  partF  = (float*)(ws + 25165824);    // 33,554,432  [64][256][512]
  float*  pooled = (float*)(ws + 58720256);    //  2,097,152  [8][256][256]
  float*  dinv   = (float*)(ws + 60817408);    //      8,192  [8][256]
  __bf16* W1T    = (__bf16*)(ws + 60825600);   //    262,144  [256][512]
  __bf16* W2T    = (__bf16*)(ws + 61087744);   //    131,072  [256][256]

  float* pfeat  = (float*)d_out;               // [8,256,512]
  float* outAdj = (float*)d_out + 1048576;     // [8,256,256]
  float* pmask  = (float*)d_out + 1572864;     // [8,256]

  prep_weights_k<<<48, 256, 0, stream>>>(W1, W2, W1T, W2T);
  assign_fused_k<<<dim3(1, 512, 1), 256, 0, stream>>>(x, W1T, W2T, b1, b2, mask, ST);
  gemm_feat_k<<<dim3(4, 1, 64), 512, 0, stream>>>(ST, x, partF);        // x still L3-hot
  reduce_feat_k<<<1024, 256, 0, stream>>>(partF, pfeat);
  gemm_adj_k<<<dim3(1, 64, 8), 256, 0, stream>>>(adj, ST, midT);
  gemm_pool_k<<<dim3(4, 4, 32), 256, 0, stream>>>(ST, midT, partP);
  reduce_pool_k<<<512, 256, 0, stream>>>(partP, pooled, dinv);
  finalize_k<<<2048, 256, 0, stream>>>(pooled, dinv, outAdj, pmask);
}

// Round 4
// 116.502 us; speedup vs baseline: 1.9280x; 1.1461x over previous
//
#include <hip/hip_runtime.h>
#include <hip/hip_bf16.h>

// NodeAggregator forward, round 4: counted-vmcnt pipelines (T3+T4) in the 3 big GEMMs.
// STE => forward output == degree-normalized pooled; top-k dead.
// Schedule per K-step: {issue B gloadlds depth-1 + A f32-reg loads depth-2} -> MFMA(cur)
//   -> vmcnt(retire A(t+1)) -> ds_write A[nxt] -> vmcnt(retire B(t+1), KEEP A(t+2) in
//   flight) -> lgkmcnt(0) -> raw s_barrier.  Never vmcnt(0) in steady state.
// Issue order pinned with sched_barrier(0) (vmcnt is FIFO); post-barrier memory-clobber
// asm stops LDS-read hoisting (rule #18).

typedef float f32x4 __attribute__((ext_vector_type(4)));
typedef __bf16 bf16x8 __attribute__((ext_vector_type(8)));

#define VMCNT(n) asm volatile("s_waitcnt vmcnt(" #n ")" ::: "memory")
#define LGKM0    asm volatile("s_waitcnt lgkmcnt(0)" ::: "memory")
#define SCHEDB   __builtin_amdgcn_sched_barrier(0)
#define BARRIER                                        \
  do {                                                 \
    LGKM0;                                             \
    __builtin_amdgcn_s_barrier();                      \
    asm volatile("" ::: "memory");                     \
    SCHEDB;                                            \
  } while (0)

__device__ __forceinline__ void async_load16(const void* g, void* l) {
  __builtin_amdgcn_global_load_lds((const __attribute__((address_space(1))) void*)g,
                                   (__attribute__((address_space(3))) void*)l, 16, 0, 0);
}
__device__ __forceinline__ unsigned short f2bf(float f) {
  return __builtin_bit_cast(unsigned short, (__bf16)f);
}
__device__ __forceinline__ ushort4 f4_to_bf4(float4 v) {
  ushort4 u; u.x = f2bf(v.x); u.y = f2bf(v.y); u.z = f2bf(v.z); u.w = f2bf(v.w); return u;
}

// T2 swizzle: gloadlds writes linear LDS; swizzle the SOURCE granule (rule #21) and
// apply the same XOR on fragment reads.
template <int ROWS, int BK, int NT>
__device__ __forceinline__ void stage_bf16(const __bf16* __restrict__ src, long long ld,
                                           __bf16* lds, int t) {
  constexpr int GR = BK / 8;
  constexpr int N = ROWS * GR / NT;
#pragma unroll
  for (int c = 0; c < N; ++c) {
    const int idx = c * NT + t;
    const int row = idx / GR;
    const int g = idx % GR;
    const int gs = g ^ (row & (GR - 1) & 7);
    async_load16(src + (long long)row * ld + gs * 8, lds + idx * 8);
  }
}
template <int BK>
__device__ __forceinline__ bf16x8 frag(const __bf16* lds, int row, int kq) {
  constexpr int GR = BK / 8;
  const int g = kq ^ (row & (GR - 1) & 7);
  return *(const bf16x8*)(lds + row * BK + g * 8);
}

// ---------------- weight transposes (tiny) ----------------
__global__ __launch_bounds__(256) void prep_weights_k(const float* __restrict__ W1,
                                                      const float* __restrict__ W2,
                                                      __bf16* __restrict__ W1T,
                                                      __bf16* __restrict__ W2T) {
  __shared__ float tile[64][65];
  int bid = blockIdx.x;
  const float* in; __bf16* out; int R, C;
  if (bid < 32) { in = W1; out = W1T; R = 512; C = 256; }
  else { bid -= 32; in = W2; out = W2T; R = 256; C = 256; }
  const int r0 = (bid >> 2) * 64, c0 = (bid & 3) * 64;
  const int tr = threadIdx.x >> 6, tc = threadIdx.x & 63;
#pragma unroll
  for (int i = 0; i < 16; ++i)
    tile[tr + i * 4][tc] = in[(long long)(r0 + tr + i * 4) * C + c0 + tc];
  __syncthreads();
#pragma unroll
  for (int i = 0; i < 16; ++i)
    out[(long long)(c0 + tr + i * 4) * R + r0 + tc] = (__bf16)tile[tc][tr + i * 4];
}

// ---------------- fused assign: relu(xW1+b1)W2+b2 -> masked softmax -> ST ----------
__device__ __forceinline__ void asg_compute(const __bf16* __restrict__ Abuf,
                                            const __bf16* __restrict__ Bbuf,
                                            f32x4 (&acc)[2][4], int wn, int l15, int l4) {
  bf16x8 af[2], bf[4];
#pragma unroll
  for (int i = 0; i < 2; ++i) af[i] = frag<32>(Abuf, i * 16 + l15, l4);
#pragma unroll
  for (int j = 0; j < 4; ++j) bf[j] = frag<32>(Bbuf, wn + j * 16 + l15, l4);
  __builtin_amdgcn_s_setprio(1);
#pragma unroll
  for (int i = 0; i < 2; ++i)
#pragma unroll
    for (int j = 0; j < 4; ++j)
      acc[i][j] = __builtin_amdgcn_mfma_f32_16x16x32_bf16(af[i], bf[j], acc[i][j], 0, 0, 0);
  __builtin_amdgcn_s_setprio(0);
}

__global__ __launch_bounds__(256) void assign_fused_k(
    const float* __restrict__ x, const __bf16* __restrict__ W1T,
    const __bf16* __restrict__ W2T, const float* __restrict__ b1,
    const float* __restrict__ b2, const float* __restrict__ mask,
    __bf16* __restrict__ ST) {
  __shared__ alignas(16) __bf16 Ax[2][32 * 32];
  __shared__ alignas(16) __bf16 Bw[2][256 * 32];
  __shared__ alignas(16) __bf16 hl[32 * 264];
  __shared__ float red[2][4][32];

  const int t = threadIdx.x;
  const int lane = t & 63, wave = t >> 6;
  const int l15 = lane & 15, l4 = lane >> 4;
  const int wn = wave * 64;
  const long long row0 = (long long)blockIdx.x * 32;
  const float* Xb = x + row0 * 512;

  const int arow = t >> 3, afq = t & 7;  // 1 float4/thread per tile
  const int ag = afq >> 1;
  const int aoff = arow * 32 + ((ag ^ (arow & 3)) * 8) + (afq & 1) * 4;

  auto ldx = [&](int tile) -> float4 {
    return *(const float4*)(Xb + (long long)arow * 512 + tile * 32 + afq * 4);
  };
  auto sta = [&](__bf16* dst, float4 v) { *(ushort4*)&dst[aoff] = f4_to_bf4(v); };

  f32x4 acc[2][4] = {};

  // prologue: queue [x0(1), W0(4)]
  float4 xA = ldx(0);
  SCHEDB;
  stage_bf16<256, 32, 256>(W1T, 512, Bw[0], t);
  SCHEDB;
  VMCNT(4); SCHEDB;           // x0 done
  sta(Ax[0], xA);
  float4 xB = ldx(1);         // queue [W0(4), x1(1)]
  SCHEDB;
  VMCNT(1); SCHEDB;           // W0 done
  BARRIER;

#pragma unroll 1
  for (int tt = 0; tt < 14; tt += 2) {
    // tile tt (cur=0): consume x(t+1)=xB, fill xA=x(t+2)
    stage_bf16<256, 32, 256>(W1T + (tt + 1) * 32, 512, Bw[1], t);
    SCHEDB;
    xA = ldx(tt + 2);
    SCHEDB;
    asg_compute(Ax[0], Bw[0], acc, wn, l15, l4);
    VMCNT(5); SCHEDB;         // retire x(t+1); queue [W(t+1)4, x(t+2)1]
    sta(Ax[1], xB);
    VMCNT(1); SCHEDB;         // retire W(t+1); keep x(t+2) in flight
    BARRIER;
    // tile tt+1 (cur=1)
    stage_bf16<256, 32, 256>(W1T + (tt + 2) * 32, 512, Bw[0], t);
    SCHEDB;
    xB = ldx(tt + 3);
    SCHEDB;
    asg_compute(Ax[1], Bw[1], acc, wn, l15, l4);
    VMCNT(5); SCHEDB;
    sta(Ax[0], xA);
    VMCNT(1); SCHEDB;
    BARRIER;
  }
  // tile 14: no x(16)
  stage_bf16<256, 32, 256>(W1T + 15 * 32, 512, Bw[1], t);
  SCHEDB;
  asg_compute(Ax[0], Bw[0], acc, wn, l15, l4);
  VMCNT(4); SCHEDB;           // retire x15; queue [W15(4)]
  sta(Ax[1], xB);
  VMCNT(0); SCHEDB;
  BARRIER;
  // tile 15
  asg_compute(Ax[1], Bw[1], acc, wn, l15, l4);

  // h = relu(acc+b1) -> LDS; stage W2 tile 0
  stage_bf16<256, 32, 256>(W2T, 256, Bw[0], t);
  SCHEDB;
#pragma unroll
  for (int j = 0; j < 4; ++j) {
    const int col = wn + j * 16 + l15;
    const float bv = b1[col];
#pragma unroll
    for (int i = 0; i < 2; ++i)
#pragma unroll
      for (int r = 0; r < 4; ++r)
        hl[(i * 16 + l4 * 4 + r) * 264 + col] = (__bf16)fmaxf(acc[i][j][r] + bv, 0.f);
  }
  VMCNT(0); SCHEDB;
  BARRIER;

  f32x4 acc2[2][4] = {};
#pragma unroll 1
  for (int tt = 0; tt < 8; ++tt) {  // phase-2: short, L2-hot; depth-1 with drain
    if (tt < 7) stage_bf16<256, 32, 256>(W2T + (tt + 1) * 32, 256, Bw[(tt & 1) ^ 1], t);
    SCHEDB;
    const __bf16* Bc = Bw[tt & 1];
    bf16x8 af[2], bf[4];
#pragma unroll
    for (int i = 0; i < 2; ++i)
      af[i] = *(const bf16x8*)(&hl[(i * 16 + l15) * 264 + tt * 32 + l4 * 8]);
#pragma unroll
    for (int j = 0; j < 4; ++j) bf[j] = frag<32>(Bc, wn + j * 16 + l15, l4);
#pragma unroll
    for (int i = 0; i < 2; ++i)
#pragma unroll
      for (int j = 0; j < 4; ++j)
        acc2[i][j] = __builtin_amdgcn_mfma_f32_16x16x32_bf16(af[i], bf[j], acc2[i][j], 0, 0, 0);
    VMCNT(0); SCHEDB;
    BARRIER;
  }

  // masked softmax over full 256 cols, transposed ST store
  float mb[2][4], mx[2][4], sm[2][4];
#pragma unroll
  for (int i = 0; i < 2; ++i)
#pragma unroll
    for (int r = 0; r < 4; ++r) {
      mb[i][r] = -1e9f * (1.0f - mask[row0 + i * 16 + l4 * 4 + r]);
      mx[i][r] = -3.4e38f;
      sm[i][r] = 0.f;
    }
#pragma unroll
  for (int j = 0; j < 4; ++j) {
    const float bv = b2[wn + j * 16 + l15];
#pragma unroll
    for (int i = 0; i < 2; ++i)
#pragma unroll
      for (int r = 0; r < 4; ++r) {
        const float v = acc2[i][j][r] + bv + mb[i][r];
        acc2[i][j][r] = v;
        mx[i][r] = fmaxf(mx[i][r], v);
      }
  }
#pragma unroll
  for (int i = 0; i < 2; ++i)
#pragma unroll
    for (int r = 0; r < 4; ++r) {
      float m = mx[i][r];
      m = fmaxf(m, __shfl_xor(m, 1, 64)); m = fmaxf(m, __shfl_xor(m, 2, 64));
      m = fmaxf(m, __shfl_xor(m, 4, 64)); m = fmaxf(m, __shfl_xor(m, 8, 64));
      mx[i][r] = m;
    }
  if (l15 == 0)
#pragma unroll
    for (int i = 0; i < 2; ++i)
#pragma unroll
      for (int r = 0; r < 4; ++r) red[0][wave][i * 16 + l4 * 4 + r] = mx[i][r];
  __syncthreads();
#pragma unroll
  for (int i = 0; i < 2; ++i)
#pragma unroll
    for (int r = 0; r < 4; ++r) {
      const int rl = i * 16 + l4 * 4 + r;
      mx[i][r] = fmaxf(fmaxf(red[0][0][rl], red[0][1][rl]),
                       fmaxf(red[0][2][rl], red[0][3][rl]));
    }
#pragma unroll
  for (int j = 0; j < 4; ++j)
#pragma unroll
    for (int i = 0; i < 2; ++i)
#pragma unroll
      for (int r = 0; r < 4; ++r) {
        const float e = __expf(acc2[i][j][r] - mx[i][r]);
        acc2[i][j][r] = e;
        sm[i][r] += e;
      }
#pragma unroll
  for (int i = 0; i < 2; ++i)
#pragma unroll
    for (int r = 0; r < 4; ++r) {
      float s = sm[i][r];
      s += __shfl_xor(s, 1, 64); s += __shfl_xor(s, 2, 64);
      s += __shfl_xor(s, 4, 64); s += __shfl_xor(s, 8, 64);
      sm[i][r] = s;
    }
  if (l15 == 0)
#pragma unroll
    for (int i = 0; i < 2; ++i)
#pragma unroll
      for (int r = 0; r < 4; ++r) red[1][wave][i * 16 + l4 * 4 + r] = sm[i][r];
  __syncthreads();
  float inv[2][4];
#pragma unroll
  for (int i = 0; i < 2; ++i)
#pragma unroll
    for (int r = 0; r < 4; ++r) {
      const int rl = i * 16 + l4 * 4 + r;
      inv[i][r] = 1.0f / (red[1][0][rl] + red[1][1][rl] + red[1][2][rl] + red[1][3][rl]);
    }
  const long long bb = row0 >> 11;
  const long long n0 = row0 & 2047;
  __bf16* Sb = ST + bb * 524288;
#pragma unroll
  for (int j = 0; j < 4; ++j) {
    const int col = wn + j * 16 + l15;
#pragma unroll
    for (int i = 0; i < 2; ++i) {
      ushort4 u;
      u.x = f2bf(acc2[i][j][0] * inv[i][0]);
      u.y = f2bf(acc2[i][j][1] * inv[i][1]);
      u.z = f2bf(acc2[i][j][2] * inv[i][2]);
      u.w = f2bf(acc2[i][j][3] * inv[i][3]);
      *(ushort4*)(Sb + (long long)col * 2048 + n0 + i * 16 + l4 * 4) = u;
    }
  }
}

// ---------------- G3: midT = (adj @ S)^T, pipelined, adj f32 read once -------------
__device__ __forceinline__ void adj_compute(const __bf16* __restrict__ Abuf,
                                            const __bf16* __restrict__ Bbuf,
                                            f32x4 (&acc)[2][4],
                                            int wm, int wn, int l15, int l4) {
#pragma unroll
  for (int ks = 0; ks < 2; ++ks) {
    bf16x8 af[2], bf[4];
#pragma unroll
    for (int i = 0; i < 2; ++i) af[i] = frag<64>(Abuf, wm + i * 16 + l15, ks * 4 + l4);
#pragma unroll
    for (int j = 0; j < 4; ++j) bf[j] = frag<64>(Bbuf, wn + j * 16 + l15, ks * 4 + l4);
    __builtin_amdgcn_s_setprio(1);
#pragma unroll
    for (int i = 0; i < 2; ++i)
#pragma unroll
      for (int j = 0; j < 4; ++j)
        acc[i][j] = __builtin_amdgcn_mfma_f32_16x16x32_bf16(af[i], bf[j], acc[i][j], 0, 0, 0);
    __builtin_amdgcn_s_setprio(0);
  }
}

__global__ __launch_bounds__(512) void gemm_adj_k(const float* __restrict__ adj,
                                                  const __bf16* __restrict__ ST,
                                                  __bf16* __restrict__ midT) {
  __shared__ alignas(16) __bf16 Aa[2][64 * 64];
  __shared__ alignas(16) __bf16 Bs[2][256 * 64];
  const int t = threadIdx.x;
  const int lane = t & 63, wave = t >> 6;
  const int l15 = lane & 15, l4 = lane >> 4;
  const int wm = (wave >> 2) * 32, wn = (wave & 3) * 64;
  const int id = blockIdx.x;              // 256 blocks; batch pinned to XCD (id&7)
  const int bz = id & 7;
  const long long r0 = (long long)(id >> 3) * 64;
  const float* Ab = adj + (long long)bz * 4194304 + r0 * 2048;
  const __bf16* Bb = ST + (long long)bz * 524288;

  const int arow = t >> 4, afq = t & 15;  // 2 float4/thread: rows arow, arow+32
  const int ag = afq >> 1;
  const int aoff0 = arow * 64 + ((ag ^ (arow & 7)) * 8) + (afq & 1) * 4;
  const int aoff1 = (arow + 32) * 64 + ((ag ^ ((arow + 32) & 7)) * 8) + (afq & 1) * 4;

  auto lda4 = [&](int tile, int half) -> float4 {
    return *(const float4*)(Ab + (long long)(arow + half * 32) * 2048 + tile * 64 + afq * 4);
  };
  auto sta = [&](__bf16* dst, float4 v0, float4 v1) {
    *(ushort4*)&dst[aoff0] = f4_to_bf4(v0);
    *(ushort4*)&dst[aoff1] = f4_to_bf4(v1);
  };

  f32x4 acc[2][4] = {};

  // prologue: queue [a0(2), B0(4)]
  float4 aA0 = lda4(0, 0), aA1 = lda4(0, 1);
  SCHEDB;
  stage_bf16<256, 64, 512>(Bb, 2048, Bs[0], t);
  SCHEDB;
  VMCNT(4); SCHEDB;            // a0 done
  sta(Aa[0], aA0, aA1);
  float4 aB0 = lda4(1, 0), aB1 = lda4(1, 1);  // queue [B0(4), a1(2)]
  SCHEDB;
  VMCNT(2); SCHEDB;            // B0 done
  BARRIER;

#pragma unroll 1
  for (int tt = 0; tt < 30; tt += 2) {
    // tile tt (cur=0): consume a(t+1)=aB, fill aA=a(t+2)
    stage_bf16<256, 64, 512>(Bb + (tt + 1) * 64, 2048, Bs[1], t);
    SCHEDB;
    aA0 = lda4(tt + 2, 0); aA1 = lda4(tt + 2, 1);
    SCHEDB;
    adj_compute(Aa[0], Bs[0], acc, wm, wn, l15, l4);
    VMCNT(6); SCHEDB;          // retire a(t+1); queue [B(t+1)4, a(t+2)2]
    sta(Aa[1], aB0, aB1);
    VMCNT(2); SCHEDB;          // retire B(t+1); keep a(t+2) flying over the barrier
    BARRIER;
    // tile tt+1 (cur=1)
    stage_bf16<256, 64, 512>(Bb + (tt + 2) * 64, 2048, Bs[0], t);
    SCHEDB;
    aB0 = lda4(tt + 3, 0); aB1 = lda4(tt + 3, 1);
    SCHEDB;
    adj_compute(Aa[1], Bs[1], acc, wm, wn, l15, l4);
    VMCNT(6); SCHEDB;
    sta(Aa[0], aA0, aA1);
    VMCNT(2); SCHEDB;
    BARRIER;
  }
  // tile 30: no a(32)
  stage_bf16<256, 64, 512>(Bb + 31 * 64, 2048, Bs[1], t);
  SCHEDB;
  adj_compute(Aa[0], Bs[0], acc, wm, wn, l15, l4);
  VMCNT(4); SCHEDB;            // retire a31; queue [B31(4)]
  sta(Aa[1], aB0, aB1);
  VMCNT(0); SCHEDB;
  BARRIER;
  // tile 31
  adj_compute(Aa[1], Bs[1], acc, wm, wn, l15, l4);

  __bf16* Cb = midT + (long long)bz * 524288;
#pragma unroll
  for (int j = 0; j < 4; ++j) {
    const int l = wn + j * 16 + l15;
#pragma unroll
    for (int i = 0; i < 2; ++i) {
      ushort4 u;
      u.x = f2bf(acc[i][j][0]); u.y = f2bf(acc[i][j][1]);
      u.z = f2bf(acc[i][j][2]); u.w = f2bf(acc[i][j][3]);
      *(ushort4*)(Cb + (long long)l * 2048 + r0 + wm + i * 16 + l4 * 4) = u;
    }
  }
}

// ---------------- G5: pfeat partials = ST @ x, split-K x8, pipelined ---------------
__device__ __forceinline__ void feat_compute(const __bf16* __restrict__ Abuf,
                                             const __bf16* __restrict__ Bbuf,
                                             f32x4 (&acc)[8][2],
                                             int wm, int wn, int l15, int l4) {
  bf16x8 af[8], bf[2];
#pragma unroll
  for (int i = 0; i < 8; ++i) af[i] = frag<32>(Abuf, wm + i * 16 + l15, l4);
#pragma unroll
  for (int j = 0; j < 2; ++j)
    bf[j] = *(const bf16x8*)(&Bbuf[(wn + j * 16 + l15) * 40 + l4 * 8]);
  __builtin_amdgcn_s_setprio(1);
#pragma unroll
  for (int i = 0; i < 8; ++i)
#pragma unroll
    for (int j = 0; j < 2; ++j)
      acc[i][j] = __builtin_amdgcn_mfma_f32_16x16x32_bf16(af[i], bf[j], acc[i][j], 0, 0, 0);
  __builtin_amdgcn_s_setprio(0);
}

__global__ __launch_bounds__(512) void gemm_feat_k(const __bf16* __restrict__ ST,
                                                   const float* __restrict__ x,
                                                   float* __restrict__ partF) {
  __shared__ alignas(16) __bf16 As[2][256 * 32];
  __shared__ alignas(16) __bf16 Bx[2][128 * 40];
  const int t = threadIdx.x;
  const int lane = t & 63, wave = t >> 6;
  const int l15 = lane & 15, l4 = lane >> 4;
  const int wm = (wave >> 2) * 128, wn = (wave & 3) * 32;
  const int gid = blockIdx.x;             // 256 blocks; batch pinned to XCD (gid&7)
  const int b = gid & 7, ks = gid >> 5, fblk = (gid >> 3) & 3;
  const int f0 = fblk * 128;
  const __bf16* Ab = ST + (long long)b * 524288 + ks * 256;
  const float* Xb = x + (long long)b * 1048576 + (long long)ks * 256 * 512 + f0;

  const int xn0 = t >> 5, xfq = t & 31;   // 2 float4/thread: n rows xn0, xn0+16
  f32x4 acc[8][2] = {};

  auto ldx = [&](int tile, int half) -> float4 {
    return *(const float4*)(Xb + (long long)(tile * 32 + half * 16 + xn0) * 512 + xfq * 4);
  };
  auto stx = [&](__bf16* dst, float4 v, int half) {
    const int n = half * 16 + xn0;
    dst[(xfq * 4 + 0) * 40 + n] = (__bf16)v.x;
    dst[(xfq * 4 + 1) * 40 + n] = (__bf16)v.y;
    dst[(xfq * 4 + 2) * 40 + n] = (__bf16)v.z;
    dst[(xfq * 4 + 3) * 40 + n] = (__bf16)v.w;
  };

  // prologue: queue [x0(2), A0(2)]
  float4 xA0 = ldx(0, 0), xA1 = ldx(0, 1);
  SCHEDB;
  stage_bf16<256, 32, 512>(Ab, 2048, As[0], t);
  SCHEDB;
  VMCNT(2); SCHEDB;            // x0 done
  stx(Bx[0], xA0, 0); stx(Bx[0], xA1, 1);
  float4 xB0 = ldx(1, 0), xB1 = ldx(1, 1);  // queue [A0(2), x1(2)]
  SCHEDB;
  VMCNT(2); SCHEDB;            // A0 done
  BARRIER;

#pragma unroll 1
  for (int tt = 0; tt < 6; tt += 2) {
    // tile tt (cur=0): consume x(t+1)=xB, fill xA=x(t+2)
    stage_bf16<256, 32, 512>(Ab + (tt + 1) * 32, 2048, As[1], t);
    SCHEDB;
    xA0 = ldx(tt + 2, 0); xA1 = ldx(tt + 2, 1);
    SCHEDB;
    feat_compute(As[0], Bx[0], acc, wm, wn, l15, l4);
    VMCNT(4); SCHEDB;          // retire x(t+1); queue [A(t+1)2, x(t+2)2]
    stx(Bx[1], xB0, 0); stx(Bx[1], xB1, 1);
    VMCNT(2); SCHEDB;          // retire A(t+1); keep x(t+2) flying
    BARRIER;
    // tile tt+1 (cur=1)
    stage_bf16<256, 32, 512>(Ab + (tt + 2) * 32, 2048, As[0], t);
    SCHEDB;
    xB0 = ldx(tt + 3, 0); xB1 = ldx(tt + 3, 1);
    SCHEDB;
    feat_compute(As[1], Bx[1], acc, wm, wn, l15, l4);
    VMCNT(4); SCHEDB;
    stx(Bx[0], xA0, 0); stx(Bx[0], xA1, 1);
    VMCNT(2); SCHEDB;
    BARRIER;
  }
  // tile 6: no x(8)
  stage_bf16<256, 32, 512>(Ab + 7 * 32, 2048, As[1], t);
  SCHEDB;
  feat_compute(As[0], Bx[0], acc, wm, wn, l15, l4);
  VMCNT(2); SCHEDB;            // retire x7; queue [A7(2)]
  stx(Bx[1], xB0, 0); stx(Bx[1], xB1, 1);
  VMCNT(0); SCHEDB;
  BARRIER;
  // tile 7
  feat_compute(As[1], Bx[1], acc, wm, wn, l15, l4);

  float* out = partF + ((long long)b * 8 + ks) * 131072;
#pragma unroll
  for (int i = 0; i < 8; ++i)
#pragma unroll
    for (int j = 0; j < 2; ++j)
#pragma unroll
      for (int r = 0; r < 4; ++r)
        out[(wm + i * 16 + l4 * 4 + r) * 512 + f0 + wn + j * 16 + l15] = acc[i][j][r];
}

// ---------------- G4: pooled partials = ST @ midT^T, split-K x4 (unchanged) --------
__global__ __launch_bounds__(256) void gemm_pool_k(const __bf16* __restrict__ ST,
                                                   const __bf16* __restrict__ midT,
                                                   float* __restrict__ partP) {
  __shared__ alignas(16) __bf16 As[2][64 * 64];
  __shared__ alignas(16) __bf16 Bs[2][64 * 64];
  const int t = threadIdx.x;
  const int lane = t & 63, wave = t >> 6;
  const int l15 = lane & 15, l4 = lane >> 4;
  const int wm = (wave >> 1) * 32, wn = (wave & 1) * 32;
  const int b = blockIdx.z >> 2, ks = blockIdx.z & 3;
  const long long row0 = (long long)blockIdx.y * 64, col0 = (long long)blockIdx.x * 64;
  const __bf16* Ab = ST + (long long)b * 524288 + row0 * 2048 + ks * 512;
  const __bf16* Bb = midT + (long long)b * 524288 + col0 * 2048 + ks * 512;

  f32x4 acc[2][2] = {};
  stage_bf16<64, 64, 256>(Ab, 2048, As[0], t);
  stage_bf16<64, 64, 256>(Bb, 2048, Bs[0], t);
  __syncthreads();
  for (int tt = 0; tt < 8; ++tt) {
    const int cur = tt & 1, nxt = cur ^ 1;
    if (tt < 7) {
      stage_bf16<64, 64, 256>(Ab + (tt + 1) * 64, 2048, As[nxt], t);
      stage_bf16<64, 64, 256>(Bb + (tt + 1) * 64, 2048, Bs[nxt], t);
    }
#pragma unroll
    for (int ksb = 0; ksb < 2; ++ksb) {
      bf16x8 af[2], bfr[2];
#pragma unroll
      for (int i = 0; i < 2; ++i) af[i] = frag<64>(As[cur], wm + i * 16 + l15, ksb * 4 + l4);
#pragma unroll
      for (int j = 0; j < 2; ++j) bfr[j] = frag<64>(Bs[cur], wn + j * 16 + l15, ksb * 4 + l4);
#pragma unroll
      for (int i = 0; i < 2; ++i)
#pragma unroll
        for (int j = 0; j < 2; ++j)
          acc[i][j] = __builtin_amdgcn_mfma_f32_16x16x32_bf16(af[i], bfr[j], acc[i][j], 0, 0, 0);
    }
    __syncthreads();
  }
  float* out = partP + (long long)blockIdx.z * 65536;
#pragma unroll
  for (int i = 0; i < 2; ++i)
#pragma unroll
    for (int j = 0; j < 2; ++j)
#pragma unroll
      for (int r = 0; r < 4; ++r)
        out[(row0 + wm + i * 16 + l4 * 4 + r) * 256 + col0 + wn + j * 16 + l15] = acc[i][j][r];
}

// ---------------- reducers / finalize ----------------
__global__ __launch_bounds__(256) void reduce_pool_k(const float* __restrict__ partP,
                                                     float* __restrict__ pooled,
                                                     float* __restrict__ dinv) {
  const int gr = blockIdx.x * 4 + (threadIdx.x >> 6);
  const int lane = threadIdx.x & 63;
  const int b = gr >> 8, row = gr & 255;
  const long long base = (long long)b * 4 * 65536 + (long long)row * 256;
  float s = 0.f;
#pragma unroll
  for (int q = 0; q < 4; ++q) {
    const int c = lane + q * 64;
    float v = partP[base + c] + partP[base + 65536 + c] +
              partP[base + 131072 + c] + partP[base + 196608 + c];
    pooled[(long long)gr * 256 + c] = v;
    s += v;
  }
#pragma unroll
  for (int o = 32; o > 0; o >>= 1) s += __shfl_xor(s, o, 64);
  if (lane == 0) dinv[gr] = rsqrtf(s + 1e-9f);
}

__global__ __launch_bounds__(256) void reduce_feat_k(const float* __restrict__ partF,
                                                     float* __restrict__ pfeat) {
  const long long p = blockIdx.x * 256LL + threadIdx.x;
  const int b = (int)(p >> 15), rc = (int)(p & 32767);
  const float4* src = (const float4*)partF;
  float4 a = {0.f, 0.f, 0.f, 0.f};
#pragma unroll
  for (int ks = 0; ks < 8; ++ks) {
    const float4 v = src[(long long)(b * 8 + ks) * 32768 + rc];
    a.x += v.x; a.y += v.y; a.z += v.z; a.w += v.w;
  }
  ((float4*)pfeat)[p] = a;
}

__global__ __launch_bounds__(256) void finalize_k(const float* __restrict__ pooled,
                                                  const float* __restrict__ dinv,
                                                  float* __restrict__ outAdj,
                                                  float* __restrict__ pmask) {
  const long long i = blockIdx.x * 256LL + threadIdx.x;
  const int c = (int)(i & 255);
  const int r = (int)((i >> 8) & 255);
  const int b = (int)(i >> 16);
  outAdj[i] = pooled[i] * dinv[b * 256 + r] * dinv[b * 256 + c];
  if (i < 2048) pmask[i] = 1.0f;
}

extern "C" void kernel_launch(void* const* d_in, const int* in_sizes, int n_in,
                              void* d_out, int out_size, void* d_ws, size_t ws_size,
                              hipStream_t stream) {
  (void)in_sizes; (void)n_in; (void)out_size; (void)ws_size;
  const float* x    = (const float*)d_in[0];  // [8,2048,512]
  const float* adj  = (const float*)d_in[1];  // [8,2048,2048]
  const float* mask = (const float*)d_in[2];  // [8,2048]
  const float* W1   = (const float*)d_in[3];  // [512,256]
  const float* b1   = (const float*)d_in[4];  // [256]
  const float* W2   = (const float*)d_in[5];  // [256,256]
  const float* b2   = (const float*)d_in[6];  // [256]

  char* ws = (char*)d_ws;  // total 61,218,816 B
  __bf16* ST     = (__bf16*)(ws + 0);          //  8,388,608  [8][256][2048]
  __bf16* midT   = (__bf16*)(ws + 8388608);    //  8,388,608  [8][256][2048]
  float*  partP  = (float*)(ws + 16777216);    //  8,388,608  [32][256][256]
  float*  partF  = (float*)(ws + 25165824);    // 33,554,432  [64][256][512]
  float*  pooled = (float*)(ws + 58720256);    //  2,097,152  [8][256][256]
  float*  dinv   = (float*)(ws + 60817408);    //      8,192  [8][256]
  __bf16* W1T    = (__bf16*)(ws + 60825600);   //    262,144  [256][512]
  __bf16* W2T    = (__bf16*)(ws + 61087744);   //    131,072  [256][256]

  float* pfeat  = (float*)d_out;               // [8,256,512]
  float* outAdj = (float*)d_out + 1048576;     // [8,256,256]
  float* pmask  = (float*)d_out + 1572864;     // [8,256]

  prep_weights_k<<<48, 256, 0, stream>>>(W1, W2, W1T, W2T);
  assign_fused_k<<<512, 256, 0, stream>>>(x, W1T, W2T, b1, b2, mask, ST);
  gemm_feat_k<<<256, 512, 0, stream>>>(ST, x, partF);   // x L3-hot from assign
  reduce_feat_k<<<1024, 256, 0, stream>>>(partF, pfeat);
  gemm_adj_k<<<256, 512, 0, stream>>>(adj, ST, midT);
  gemm_pool_k<<<dim3(4, 4, 32), 256, 0, stream>>>(ST, midT, partP);
  reduce_pool_k<<<512, 256, 0, stream>>>(partP, pooled, dinv);
  finalize_k<<<2048, 256, 0, stream>>>(pooled, dinv, outAdj, pmask);
}

// Round 5
// 113.362 us; speedup vs baseline: 1.9815x; 1.0277x over previous
//
#include <hip/hip_runtime.h>
#include <hip/hip_bf16.h>

// NodeAggregator forward, round 5.
// STE => forward output == degree-normalized pooled; top-k dead.
// prep (x->xbT transpose + W1T/W2T) -> assign_fused (x@W1 relu @W2 softmax -> ST)
//   -> gemm_feat (pfeat = ST@xbT, direct write, pure-bf16 gloadlds)
//   -> gemm_adj (midT = (adj@S)^T, f32 once, counted-vmcnt depth-2, 2 blocks/CU)
//   -> gemm_pool (pooled = ST@midT direct) -> rowsum -> finalize.

typedef float f32x4 __attribute__((ext_vector_type(4)));
typedef __bf16 bf16x8 __attribute__((ext_vector_type(8)));

#define VMCNT(n) asm volatile("s_waitcnt vmcnt(" #n ")" ::: "memory")
#define LGKM0    asm volatile("s_waitcnt lgkmcnt(0)" ::: "memory")
#define SCHEDB   __builtin_amdgcn_sched_barrier(0)
#define BARRIER                                        \
  do {                                                 \
    LGKM0;                                             \
    __builtin_amdgcn_s_barrier();                      \
    asm volatile("" ::: "memory");                     \
    SCHEDB;                                            \
  } while (0)

__device__ __forceinline__ void async_load16(const void* g, void* l) {
  __builtin_amdgcn_global_load_lds((const __attribute__((address_space(1))) void*)g,
                                   (__attribute__((address_space(3))) void*)l, 16, 0, 0);
}
__device__ __forceinline__ unsigned short f2bf(float f) {
  return __builtin_bit_cast(unsigned short, (__bf16)f);
}
__device__ __forceinline__ ushort4 f4_to_bf4(float4 v) {
  ushort4 u; u.x = f2bf(v.x); u.y = f2bf(v.y); u.z = f2bf(v.z); u.w = f2bf(v.w); return u;
}

// T2 swizzle on the SOURCE granule (rule #21); LDS stays linear for gloadlds.
template <int ROWS, int BK, int NT>
__device__ __forceinline__ void stage_bf16(const __bf16* __restrict__ src, long long ld,
                                           __bf16* lds, int t) {
  constexpr int GR = BK / 8;
  constexpr int N = ROWS * GR / NT;
  static_assert(N >= 1, "stage too small");
#pragma unroll
  for (int c = 0; c < N; ++c) {
    const int idx = c * NT + t;
    const int row = idx / GR;
    const int g = idx % GR;
    const int gs = g ^ (row & (GR - 1) & 7);
    async_load16(src + (long long)row * ld + gs * 8, lds + idx * 8);
  }
}
template <int BK>
__device__ __forceinline__ bf16x8 frag(const __bf16* lds, int row, int kq) {
  constexpr int GR = BK / 8;
  const int g = kq ^ (row & (GR - 1) & 7);
  return *(const bf16x8*)(lds + row * BK + g * 8);
}

// ---------------- prep: x [8,2048,512] f32 -> xbT [8,512,2048] bf16; W1T; W2T ------
__global__ __launch_bounds__(256) void prep_k(const float* __restrict__ x,
                                              const float* __restrict__ W1,
                                              const float* __restrict__ W2,
                                              __bf16* __restrict__ xbT,
                                              __bf16* __restrict__ W1T,
                                              __bf16* __restrict__ W2T) {
  __shared__ float tile[64][65];
  const int tr = threadIdx.x >> 6, tc = threadIdx.x & 63;
  const int bid = blockIdx.x;
  const float* in; __bf16* out; int r0, c0, C, R;
  if (bid < 2048) {  // x-transpose: rows n (2048), cols f (512)
    const int fb = bid >> 8, rest = bid & 255;
    const int nb = rest >> 3, b = rest & 7;
    in = x + (long long)b * 1048576; out = xbT + (long long)b * 1048576;
    r0 = nb * 64; c0 = fb * 64; R = 2048; C = 512;
  } else if (bid < 2080) {  // W1 512x256
    const int w = bid - 2048;
    in = W1; out = W1T; r0 = (w >> 2) * 64; c0 = (w & 3) * 64; R = 512; C = 256;
  } else {                  // W2 256x256
    const int w = bid - 2080;
    in = W2; out = W2T; r0 = (w >> 2) * 64; c0 = (w & 3) * 64; R = 256; C = 256;
  }
#pragma unroll
  for (int i = 0; i < 16; ++i)
    tile[tr + i * 4][tc] = in[(long long)(r0 + tr + i * 4) * C + c0 + tc];
  __syncthreads();
#pragma unroll
  for (int i = 0; i < 16; ++i)
    out[(long long)(c0 + tr + i * 4) * R + r0 + tc] = (__bf16)tile[tc][tr + i * 4];
}

// ---------------- fused assign (unchanged from round 4, verified) ------------------
__device__ __forceinline__ void asg_compute(const __bf16* __restrict__ Abuf,
                                            const __bf16* __restrict__ Bbuf,
                                            f32x4 (&acc)[2][4], int wn, int l15, int l4) {
  bf16x8 af[2], bf[4];
#pragma unroll
  for (int i = 0; i < 2; ++i) af[i] = frag<32>(Abuf, i * 16 + l15, l4);
#pragma unroll
  for (int j = 0; j < 4; ++j) bf[j] = frag<32>(Bbuf, wn + j * 16 + l15, l4);
  __builtin_amdgcn_s_setprio(1);
#pragma unroll
  for (int i = 0; i < 2; ++i)
#pragma unroll
    for (int j = 0; j < 4; ++j)
      acc[i][j] = __builtin_amdgcn_mfma_f32_16x16x32_bf16(af[i], bf[j], acc[i][j], 0, 0, 0);
  __builtin_amdgcn_s_setprio(0);
}

__global__ __launch_bounds__(256) void assign_fused_k(
    const float* __restrict__ x, const __bf16* __restrict__ W1T,
    const __bf16* __restrict__ W2T, const float* __restrict__ b1,
    const float* __restrict__ b2, const float* __restrict__ mask,
    __bf16* __restrict__ ST) {
  __shared__ alignas(16) __bf16 Ax[2][32 * 32];
  __shared__ alignas(16) __bf16 Bw[2][256 * 32];
  __shared__ alignas(16) __bf16 hl[32 * 264];
  __shared__ float red[2][4][32];

  const int t = threadIdx.x;
  const int lane = t & 63, wave = t >> 6;
  const int l15 = lane & 15, l4 = lane >> 4;
  const int wn = wave * 64;
  const long long row0 = (long long)blockIdx.x * 32;
  const float* Xb = x + row0 * 512;

  const int arow = t >> 3, afq = t & 7;
  const int ag = afq >> 1;
  const int aoff = arow * 32 + ((ag ^ (arow & 3)) * 8) + (afq & 1) * 4;

  auto ldx = [&](int tile) -> float4 {
    return *(const float4*)(Xb + (long long)arow * 512 + tile * 32 + afq * 4);
  };
  auto sta = [&](__bf16* dst, float4 v) { *(ushort4*)&dst[aoff] = f4_to_bf4(v); };

  f32x4 acc[2][4] = {};

  float4 xA = ldx(0);
  SCHEDB;
  stage_bf16<256, 32, 256>(W1T, 512, Bw[0], t);
  SCHEDB;
  VMCNT(4); SCHEDB;
  sta(Ax[0], xA);
  float4 xB = ldx(1);
  SCHEDB;
  VMCNT(1); SCHEDB;
  BARRIER;

#pragma unroll 1
  for (int tt = 0; tt < 14; tt += 2) {
    stage_bf16<256, 32, 256>(W1T + (tt + 1) * 32, 512, Bw[1], t);
    SCHEDB;
    xA = ldx(tt + 2);
    SCHEDB;
    asg_compute(Ax[0], Bw[0], acc, wn, l15, l4);
    VMCNT(5); SCHEDB;
    sta(Ax[1], xB);
    VMCNT(1); SCHEDB;
    BARRIER;
    stage_bf16<256, 32, 256>(W1T + (tt + 2) * 32, 512, Bw[0], t);
    SCHEDB;
    xB = ldx(tt + 3);
    SCHEDB;
    asg_compute(Ax[1], Bw[1], acc, wn, l15, l4);
    VMCNT(5); SCHEDB;
    sta(Ax[0], xA);
    VMCNT(1); SCHEDB;
    BARRIER;
  }
  stage_bf16<256, 32, 256>(W1T + 15 * 32, 512, Bw[1], t);
  SCHEDB;
  asg_compute(Ax[0], Bw[0], acc, wn, l15, l4);
  VMCNT(4); SCHEDB;
  sta(Ax[1], xB);
  VMCNT(0); SCHEDB;
  BARRIER;
  asg_compute(Ax[1], Bw[1], acc, wn, l15, l4);

  stage_bf16<256, 32, 256>(W2T, 256, Bw[0], t);
  SCHEDB;
#pragma unroll
  for (int j = 0; j < 4; ++j) {
    const int col = wn + j * 16 + l15;
    const float bv = b1[col];
#pragma unroll
    for (int i = 0; i < 2; ++i)
#pragma unroll
      for (int r = 0; r < 4; ++r)
        hl[(i * 16 + l4 * 4 + r) * 264 + col] = (__bf16)fmaxf(acc[i][j][r] + bv, 0.f);
  }
  VMCNT(0); SCHEDB;
  BARRIER;

  f32x4 acc2[2][4] = {};
#pragma unroll 1
  for (int tt = 0; tt < 8; ++tt) {
    if (tt < 7) stage_bf16<256, 32, 256>(W2T + (tt + 1) * 32, 256, Bw[(tt & 1) ^ 1], t);
    SCHEDB;
    const __bf16* Bc = Bw[tt & 1];
    bf16x8 af[2], bf[4];
#pragma unroll
    for (int i = 0; i < 2; ++i)
      af[i] = *(const bf16x8*)(&hl[(i * 16 + l15) * 264 + tt * 32 + l4 * 8]);
#pragma unroll
    for (int j = 0; j < 4; ++j) bf[j] = frag<32>(Bc, wn + j * 16 + l15, l4);
#pragma unroll
    for (int i = 0; i < 2; ++i)
#pragma unroll
      for (int j = 0; j < 4; ++j)
        acc2[i][j] = __builtin_amdgcn_mfma_f32_16x16x32_bf16(af[i], bf[j], acc2[i][j], 0, 0, 0);
    VMCNT(0); SCHEDB;
    BARRIER;
  }

  float mb[2][4], mx[2][4], sm[2][4];
#pragma unroll
  for (int i = 0; i < 2; ++i)
#pragma unroll
    for (int r = 0; r < 4; ++r) {
      mb[i][r] = -1e9f * (1.0f - mask[row0 + i * 16 + l4 * 4 + r]);
      mx[i][r] = -3.4e38f;
      sm[i][r] = 0.f;
    }
#pragma unroll
  for (int j = 0; j < 4; ++j) {
    const float bv = b2[wn + j * 16 + l15];
#pragma unroll
    for (int i = 0; i < 2; ++i)
#pragma unroll
      for (int r = 0; r < 4; ++r) {
        const float v = acc2[i][j][r] + bv + mb[i][r];
        acc2[i][j][r] = v;
        mx[i][r] = fmaxf(mx[i][r], v);
      }
  }
#pragma unroll
  for (int i = 0; i < 2; ++i)
#pragma unroll
    for (int r = 0; r < 4; ++r) {
      float m = mx[i][r];
      m = fmaxf(m, __shfl_xor(m, 1, 64)); m = fmaxf(m, __shfl_xor(m, 2, 64));
      m = fmaxf(m, __shfl_xor(m, 4, 64)); m = fmaxf(m, __shfl_xor(m, 8, 64));
      mx[i][r] = m;
    }
  if (l15 == 0)
#pragma unroll
    for (int i = 0; i < 2; ++i)
#pragma unroll
      for (int r = 0; r < 4; ++r) red[0][wave][i * 16 + l4 * 4 + r] = mx[i][r];
  __syncthreads();
#pragma unroll
  for (int i = 0; i < 2; ++i)
#pragma unroll
    for (int r = 0; r < 4; ++r) {
      const int rl = i * 16 + l4 * 4 + r;
      mx[i][r] = fmaxf(fmaxf(red[0][0][rl], red[0][1][rl]),
                       fmaxf(red[0][2][rl], red[0][3][rl]));
    }
#pragma unroll
  for (int j = 0; j < 4; ++j)
#pragma unroll
    for (int i = 0; i < 2; ++i)
#pragma unroll
      for (int r = 0; r < 4; ++r) {
        const float e = __expf(acc2[i][j][r] - mx[i][r]);
        acc2[i][j][r] = e;
        sm[i][r] += e;
      }
#pragma unroll
  for (int i = 0; i < 2; ++i)
#pragma unroll
    for (int r = 0; r < 4; ++r) {
      float s = sm[i][r];
      s += __shfl_xor(s, 1, 64); s += __shfl_xor(s, 2, 64);
      s += __shfl_xor(s, 4, 64); s += __shfl_xor(s, 8, 64);
      sm[i][r] = s;
    }
  if (l15 == 0)
#pragma unroll
    for (int i = 0; i < 2; ++i)
#pragma unroll
      for (int r = 0; r < 4; ++r) red[1][wave][i * 16 + l4 * 4 + r] = sm[i][r];
  __syncthreads();
  float inv[2][4];
#pragma unroll
  for (int i = 0; i < 2; ++i)
#pragma unroll
    for (int r = 0; r < 4; ++r) {
      const int rl = i * 16 + l4 * 4 + r;
      inv[i][r] = 1.0f / (red[1][0][rl] + red[1][1][rl] + red[1][2][rl] + red[1][3][rl]);
    }
  const long long bb = row0 >> 11;
  const long long n0 = row0 & 2047;
  __bf16* Sb = ST + bb * 524288;
#pragma unroll
  for (int j = 0; j < 4; ++j) {
    const int col = wn + j * 16 + l15;
#pragma unroll
    for (int i = 0; i < 2; ++i) {
      ushort4 u;
      u.x = f2bf(acc2[i][j][0] * inv[i][0]);
      u.y = f2bf(acc2[i][j][1] * inv[i][1]);
      u.z = f2bf(acc2[i][j][2] * inv[i][2]);
      u.w = f2bf(acc2[i][j][3] * inv[i][3]);
      *(ushort4*)(Sb + (long long)col * 2048 + n0 + i * 16 + l4 * 4) = u;
    }
  }
}

// ---------------- G3: midT = (adj @ S)^T; BM=32, 256 thr, 512 blocks (2/CU) --------
__device__ __forceinline__ void adj_compute(const __bf16* __restrict__ Abuf,
                                            const __bf16* __restrict__ Bbuf,
                                            f32x4 (&acc)[2][4],
                                            int wn, int l15, int l4) {
#pragma unroll
  for (int ks = 0; ks < 2; ++ks) {
    bf16x8 af[2], bf[4];
#pragma unroll
    for (int i = 0; i < 2; ++i) af[i] = frag<64>(Abuf, i * 16 + l15, ks * 4 + l4);
#pragma unroll
    for (int j = 0; j < 4; ++j) bf[j] = frag<64>(Bbuf, wn + j * 16 + l15, ks * 4 + l4);
    __builtin_amdgcn_s_setprio(1);
#pragma unroll
    for (int i = 0; i < 2; ++i)
#pragma unroll
      for (int j = 0; j < 4; ++j)
        acc[i][j] = __builtin_amdgcn_mfma_f32_16x16x32_bf16(af[i], bf[j], acc[i][j], 0, 0, 0);
    __builtin_amdgcn_s_setprio(0);
  }
}

__global__ __launch_bounds__(256) void gemm_adj_k(const float* __restrict__ adj,
                                                  const __bf16* __restrict__ ST,
                                                  __bf16* __restrict__ midT) {
  __shared__ alignas(16) __bf16 Aa[2][32 * 64];   //  8 KB
  __shared__ alignas(16) __bf16 Bs[2][256 * 64];  // 64 KB
  const int t = threadIdx.x;
  const int lane = t & 63, wave = t >> 6;
  const int l15 = lane & 15, l4 = lane >> 4;
  const int wn = wave * 64;
  const int id = blockIdx.x;              // 512 blocks; batch pinned to XCD (id&7)
  const int bz = id & 7;
  const long long r0 = (long long)(id >> 3) * 32;
  const float* Ab = adj + (long long)bz * 4194304 + r0 * 2048;
  const __bf16* Bb = ST + (long long)bz * 524288;

  const int arow = t >> 4, afq = t & 15;  // 2 float4/thread: rows arow, arow+16
  const int ag = afq >> 1;
  const int aoff0 = arow * 64 + ((ag ^ (arow & 7)) * 8) + (afq & 1) * 4;
  const int aoff1 = (arow + 16) * 64 + ((ag ^ ((arow + 16) & 7)) * 8) + (afq & 1) * 4;

  auto lda4 = [&](int tile, int half) -> float4 {
    return *(const float4*)(Ab + (long long)(arow + half * 16) * 2048 + tile * 64 + afq * 4);
  };
  auto sta = [&](__bf16* dst, float4 v0, float4 v1) {
    *(ushort4*)&dst[aoff0] = f4_to_bf4(v0);
    *(ushort4*)&dst[aoff1] = f4_to_bf4(v1);
  };

  f32x4 acc[2][4] = {};

  // prologue: queue [a0(2), B0(8)]
  float4 aA0 = lda4(0, 0), aA1 = lda4(0, 1);
  SCHEDB;
  stage_bf16<256, 64, 256>(Bb, 2048, Bs[0], t);
  SCHEDB;
  VMCNT(8); SCHEDB;            // a0 done
  sta(Aa[0], aA0, aA1);
  float4 aB0 = lda4(1, 0), aB1 = lda4(1, 1);  // queue [B0(8), a1(2)]
  SCHEDB;
  VMCNT(2); SCHEDB;            // B0 done
  BARRIER;

#pragma unroll 1
  for (int tt = 0; tt < 30; tt += 2) {
    stage_bf16<256, 64, 256>(Bb + (tt + 1) * 64, 2048, Bs[1], t);
    SCHEDB;
    aA0 = lda4(tt + 2, 0); aA1 = lda4(tt + 2, 1);
    SCHEDB;
    adj_compute(Aa[0], Bs[0], acc, wn, l15, l4);
    VMCNT(10); SCHEDB;         // retire a(t+1); queue [B(t+1)8, a(t+2)2]
    sta(Aa[1], aB0, aB1);
    VMCNT(2); SCHEDB;          // retire B(t+1); a(t+2) stays in flight
    BARRIER;
    stage_bf16<256, 64, 256>(Bb + (tt + 2) * 64, 2048, Bs[0], t);
    SCHEDB;
    aB0 = lda4(tt + 3, 0); aB1 = lda4(tt + 3, 1);
    SCHEDB;
    adj_compute(Aa[1], Bs[1], acc, wn, l15, l4);
    VMCNT(10); SCHEDB;
    sta(Aa[0], aA0, aA1);
    VMCNT(2); SCHEDB;
    BARRIER;
  }
  stage_bf16<256, 64, 256>(Bb + 31 * 64, 2048, Bs[1], t);
  SCHEDB;
  adj_compute(Aa[0], Bs[0], acc, wn, l15, l4);
  VMCNT(8); SCHEDB;            // retire a31; queue [B31(8)]
  sta(Aa[1], aB0, aB1);
  VMCNT(0); SCHEDB;
  BARRIER;
  adj_compute(Aa[1], Bs[1], acc, wn, l15, l4);

  __bf16* Cb = midT + (long long)bz * 524288;
#pragma unroll
  for (int j = 0; j < 4; ++j) {
    const int l = wn + j * 16 + l15;
#pragma unroll
    for (int i = 0; i < 2; ++i) {
      ushort4 u;
      u.x = f2bf(acc[i][j][0]); u.y = f2bf(acc[i][j][1]);
      u.z = f2bf(acc[i][j][2]); u.w = f2bf(acc[i][j][3]);
      *(ushort4*)(Cb + (long long)l * 2048 + r0 + i * 16 + l4 * 4) = u;
    }
  }
}

// ---------------- G5: pfeat = ST @ xbT^T, direct write, pure-bf16 ------------------
// BM=32 (k), BN=64 (f), BK=64 (n); 256 thr, 4 waves 1x4 (wave tile 32x16).
__global__ __launch_bounds__(256) void gemm_feat_k(const __bf16* __restrict__ ST,
                                                   const __bf16* __restrict__ xbT,
                                                   float* __restrict__ pfeat) {
  __shared__ alignas(16) __bf16 As[2][32 * 64];  //  8 KB
  __shared__ alignas(16) __bf16 Bs[2][64 * 64];  // 16 KB
  const int t = threadIdx.x;
  const int lane = t & 63, wave = t >> 6;
  const int l15 = lane & 15, l4 = lane >> 4;
  const int wn = wave * 16;
  const int id = blockIdx.x;   // 512: b=id&7 (XCD pin), kblk fastest within XCD
  const int b = id & 7, j7 = id >> 3;
  const int kblk = j7 & 7, fblk = j7 >> 3;
  const __bf16* Ab = ST + (long long)b * 524288 + (long long)kblk * 32 * 2048;
  const __bf16* Bb = xbT + (long long)b * 1048576 + (long long)fblk * 64 * 2048;

  f32x4 acc[2] = {};
  stage_bf16<32, 64, 256>(Ab, 2048, As[0], t);
  stage_bf16<64, 64, 256>(Bb, 2048, Bs[0], t);
  __syncthreads();
#pragma unroll 1
  for (int tt = 0; tt < 32; ++tt) {  // K = 2048
    const int cur = tt & 1;
    if (tt < 31) {
      stage_bf16<32, 64, 256>(Ab + (tt + 1) * 64, 2048, As[cur ^ 1], t);
      stage_bf16<64, 64, 256>(Bb + (tt + 1) * 64, 2048, Bs[cur ^ 1], t);
    }
#pragma unroll
    for (int ks = 0; ks < 2; ++ks) {
      bf16x8 af[2], bf;
#pragma unroll
      for (int i = 0; i < 2; ++i) af[i] = frag<64>(As[cur], i * 16 + l15, ks * 4 + l4);
      bf = frag<64>(Bs[cur], wn + l15, ks * 4 + l4);
#pragma unroll
      for (int i = 0; i < 2; ++i)
        acc[i] = __builtin_amdgcn_mfma_f32_16x16x32_bf16(af[i], bf, acc[i], 0, 0, 0);
    }
    __syncthreads();
  }
  float* out = pfeat + (long long)b * 131072;
#pragma unroll
  for (int i = 0; i < 2; ++i)
#pragma unroll
    for (int r = 0; r < 4; ++r)
      out[(long long)(kblk * 32 + i * 16 + l4 * 4 + r) * 512 + fblk * 64 + wn + l15] =
          acc[i][r];
}

// ---------------- G4: pooled = ST @ midT^T, direct write --------------------------
// BM=32 (k), BN=32 (l), BK=64 (n); 256 thr, 4 waves 2x2 (wave tile 16x16).
__global__ __launch_bounds__(256) void gemm_pool_k(const __bf16* __restrict__ ST,
                                                   const __bf16* __restrict__ midT,
                                                   float* __restrict__ pooled) {
  __shared__ alignas(16) __bf16 As[2][32 * 64];
  __shared__ alignas(16) __bf16 Bs[2][32 * 64];
  const int t = threadIdx.x;
  const int lane = t & 63, wave = t >> 6;
  const int l15 = lane & 15, l4 = lane >> 4;
  const int wm = (wave >> 1) * 16, wn = (wave & 1) * 16;
  const int id = blockIdx.x;   // 512: b=id&7, kblk fastest within XCD
  const int b = id & 7, j7 = id >> 3;
  const int kblk = j7 & 7, lblk = j7 >> 3;
  const __bf16* Ab = ST + (long long)b * 524288 + (long long)kblk * 32 * 2048;
  const __bf16* Bb = midT + (long long)b * 524288 + (long long)lblk * 32 * 2048;

  f32x4 acc = {};
  stage_bf16<32, 64, 256>(Ab, 2048, As[0], t);
  stage_bf16<32, 64, 256>(Bb, 2048, Bs[0], t);
  __syncthreads();
#pragma unroll 1
  for (int tt = 0; tt < 32; ++tt) {
    const int cur = tt & 1;
    if (tt < 31) {
      stage_bf16<32, 64, 256>(Ab + (tt + 1) * 64, 2048, As[cur ^ 1], t);
      stage_bf16<32, 64, 256>(Bb + (tt + 1) * 64, 2048, Bs[cur ^ 1], t);
    }
#pragma unroll
    for (int ks = 0; ks < 2; ++ks) {
      bf16x8 af = frag<64>(As[cur], wm + l15, ks * 4 + l4);
      bf16x8 bf = frag<64>(Bs[cur], wn + l15, ks * 4 + l4);
      acc = __builtin_amdgcn_mfma_f32_16x16x32_bf16(af, bf, acc, 0, 0, 0);
    }
    __syncthreads();
  }
  float* out = pooled + (long long)b * 65536;
#pragma unroll
  for (int r = 0; r < 4; ++r)
    out[(long long)(kblk * 32 + wm + l4 * 4 + r) * 256 + lblk * 32 + wn + l15] = acc[r];
}

// ---------------- rowsum -> dinv; finalize ----------------
__global__ __launch_bounds__(256) void rowsum_k(const float* __restrict__ pooled,
                                                float* __restrict__ dinv) {
  const int gr = blockIdx.x * 4 + (threadIdx.x >> 6);  // 2048 rows
  const int lane = threadIdx.x & 63;
  const float* p = pooled + (long long)gr * 256;
  float s = p[lane] + p[lane + 64] + p[lane + 128] + p[lane + 192];
#pragma unroll
  for (int o = 32; o > 0; o >>= 1) s += __shfl_xor(s, o, 64);
  if (lane == 0) dinv[gr] = rsqrtf(s + 1e-9f);
}

__global__ __launch_bounds__(256) void finalize_k(const float* __restrict__ pooled,
                                                  const float* __restrict__ dinv,
                                                  float* __restrict__ outAdj,
                                                  float* __restrict__ pmask) {
  const long long i = blockIdx.x * 256LL + threadIdx.x;  // 524288
  const int c = (int)(i & 255);
  const int r = (int)((i >> 8) & 255);
  const int b = (int)(i >> 16);
  outAdj[i] = pooled[i] * dinv[b * 256 + r] * dinv[b * 256 + c];
  if (i < 2048) pmask[i] = 1.0f;
}

extern "C" void kernel_launch(void* const* d_in, const int* in_sizes, int n_in,
                              void* d_out, int out_size, void* d_ws, size_t ws_size,
                              hipStream_t stream) {
  (void)in_sizes; (void)n_in; (void)out_size; (void)ws_size;
  const float* x    = (const float*)d_in[0];  // [8,2048,512]
  const float* adj  = (const float*)d_in[1];  // [8,2048,2048]
  const float* mask = (const float*)d_in[2];  // [8,2048]
  const float* W1   = (const float*)d_in[3];  // [512,256]
  const float* b1   = (const float*)d_in[4];  // [256]
  const float* W2   = (const float*)d_in[5];  // [256,256]
  const float* b2   = (const float*)d_in[6];  // [256]

  char* ws = (char*)d_ws;  // total 36,052,992 B (~34.4 MiB)
  __bf16* ST     = (__bf16*)(ws + 0);          //  8,388,608  [8][256][2048]
  __bf16* midT   = (__bf16*)(ws + 8388608);    //  8,388,608  [8][256][2048]
  __bf16* xbT    = (__bf16*)(ws + 16777216);   // 16,777,216  [8][512][2048]
  float*  pooled = (float*)(ws + 33554432);    //  2,097,152  [8][256][256]
  float*  dinv   = (float*)(ws + 35651584);    //      8,192  [8][256]
  __bf16* W1T    = (__bf16*)(ws + 35659776);   //    262,144  [256][512]
  __bf16* W2T    = (__bf16*)(ws + 35921920);   //    131,072  [256][256]

  float* pfeat  = (float*)d_out;               // [8,256,512]
  float* outAdj = (float*)d_out + 1048576;     // [8,256,256]
  float* pmask  = (float*)d_out + 1572864;     // [8,256]

  prep_k<<<2096, 256, 0, stream>>>(x, W1, W2, xbT, W1T, W2T);
  assign_fused_k<<<512, 256, 0, stream>>>(x, W1T, W2T, b1, b2, mask, ST);
  gemm_feat_k<<<512, 256, 0, stream>>>(ST, xbT, pfeat);
  gemm_adj_k<<<512, 256, 0, stream>>>(adj, ST, midT);
  gemm_pool_k<<<512, 256, 0, stream>>>(ST, midT, pooled);
  rowsum_k<<<512, 256, 0, stream>>>(pooled, dinv);
  finalize_k<<<2048, 256, 0, stream>>>(pooled, dinv, outAdj, pmask);
}